// Round 9
// baseline (5799.007 us; speedup 1.0000x reference)
//
#include <hip/hip_runtime.h>
#include <stdint.h>

#define DD 256
#define NEDGE 300000
#define NNODE 100000
#define NLAY 9
#define LN_EPS 1e-5f

// LDS map (dynamic, 116736 B): W slots @0/16384/32768 (3x16KB),
// A0 @49152, A1 @81920 (2x32KB; current A doubles as hidden), red @114688.
#define LDS_A0 49152
#define LDS_A1 81920
#define LDS_RED 114688
#define LDS_TOTAL 116736

typedef __attribute__((ext_vector_type(8))) short bf16x8;
typedef __attribute__((ext_vector_type(4))) short s16x4;
typedef __attribute__((ext_vector_type(4))) float f32x4;
typedef __attribute__((ext_vector_type(4))) int i32x4;

static __device__ __forceinline__ short f2bf(float f) {
  union { float f; uint32_t u; } v; v.f = f;
  uint32_t r = (v.u + 0x7FFFu + ((v.u >> 16) & 1u)) >> 16;
  return (short)(uint16_t)r;
}
static __device__ __forceinline__ float bf2f(short s) {
  union { uint32_t u; float f; } v; v.u = ((uint32_t)(uint16_t)s) << 16;
  return v.f;
}

static __device__ __forceinline__ void gld16(const void* g, void* l) {
  __builtin_amdgcn_global_load_lds((const __attribute__((address_space(1))) void*)g,
                                   (__attribute__((address_space(3))) void*)l, 16, 0, 0);
}
#define SBAR() do { __builtin_amdgcn_s_barrier(); __builtin_amdgcn_sched_barrier(0); } while (0)

// ---------------------------------------------------------------------------
// Weight pre-transpose + bf16: dst chunk j (16B) = kq*256+col holds
// W[col][kq*8..kq*8+7] -> slice s = chunks [s*1024, s*1024+1024).
// ---------------------------------------------------------------------------
__global__ void cvtw_kernel(const float* __restrict__ src, short* __restrict__ dst, int nmat) {
  const int total = nmat * 8192;
  for (int j = blockIdx.x * blockDim.x + threadIdx.x; j < total; j += gridDim.x * blockDim.x) {
    const int m = j >> 13;
    const int jj = j & 8191;
    const int col = jj & 255;
    const int kq = jj >> 8;
    const float* s = src + (size_t)m * 65536 + col * 256 + kq * 8;
    const f32x4 u0 = *(const f32x4*)(s);
    const f32x4 u1 = *(const f32x4*)(s + 4);
    bf16x8 o;
#pragma unroll
    for (int q = 0; q < 4; ++q) { o[q] = f2bf(u0[q]); o[q + 4] = f2bf(u1[q]); }
    *(bf16x8*)(dst + (size_t)j * 8) = o;
  }
}

// ---------------------------------------------------------------------------
// Fused MLP v9 — counted-vmcnt schedule (T3/T4).
// 512 thr = 8 waves; tile 64r x 256c; wave = 32r x 64c (acc[2][4]).
// W: 16KB/slice via glds into 3 rotating slots, staged 2 K-steps ahead;
// end-of-step = s_waitcnt vmcnt(2|6) + raw s_barrier (NEVER vmcnt(0) in loop).
// A: whole 32KB tile staged once (XOR-preswizzled source); next-tile A staged
// at GEMM2 step 0; hidden aliases the current (dead) A buffer.
// ---------------------------------------------------------------------------
template<bool A_BF16, bool NODE>
__global__ __launch_bounds__(512, 2) void mlp_kernel(
    const void* __restrict__ Ain, const int* __restrict__ rowmap,
    const short* __restrict__ W1t, const short* __restrict__ W2t,
    const float* __restrict__ B1, const float* __restrict__ B2,
    const float* __restrict__ LG, const float* __restrict__ LB,
    short* __restrict__ OutB, float* __restrict__ OutF,
    const float* __restrict__ Resid, short* __restrict__ XbOut, int M) {
  extern __shared__ char smem[];
  float* redbuf = (float*)(smem + LDS_RED);
  const int tid = threadIdx.x;
  const int lane = tid & 63;
  const int wv = tid >> 6;
  const int wm = wv >> 2, wn = wv & 3;
  const int l15 = lane & 15, lq = lane >> 4;
  const int cbase = wn * 64;
  const int ntiles = (M + 63) >> 6;

  float b1v[4], b2v[4], gv[4], bvv[4];
#pragma unroll
  for (int ni = 0; ni < 4; ++ni) {
    const int c = cbase + ni * 16 + l15;
    b1v[ni] = B1[c]; b2v[ni] = B2[c]; gv[ni] = LG[c]; bvv[ni] = LB[c];
  }

  auto stageW = [&](const short* Wt, int s, int so) {
#pragma unroll
    for (int j = 0; j < 2; ++j) {
      const int c = tid + 512 * j;
      gld16(Wt + ((size_t)s * 1024 + c) * 8, smem + so + c * 16);
    }
  };
  // bf16 A: 2048 16B chunks; LDS (row, ks) holds global kq = ks ^ (row&31).
  auto stageA = [&](int tt, int ao) {
    const short* A = (const short*)Ain;
#pragma unroll
    for (int j = 0; j < 4; ++j) {
      const int c = tid + 512 * j;
      const int row = c >> 5, ks = c & 31;
      const int gr = min(tt * 64 + row, M - 1);
      const int gk = ks ^ (row & 31);
      gld16(A + (size_t)gr * DD + gk * 8, smem + ao + c * 16);
    }
  };
  auto stageA_f32 = [&](int tt, int ao) {  // fallback: reg-load + cvt + ds_write
    const float* A = (const float*)Ain;
#pragma unroll
    for (int j = 0; j < 4; ++j) {
      const int c = tid + 512 * j;
      const int row = c >> 5, ks = c & 31;
      const int gr0 = min(tt * 64 + row, M - 1);
      const int gr = rowmap ? rowmap[gr0] : gr0;
      const int gk = ks ^ (row & 31);
      const f32x4 u0 = *(const f32x4*)(A + (size_t)gr * DD + gk * 8);
      const f32x4 u1 = *(const f32x4*)(A + (size_t)gr * DD + gk * 8 + 4);
      bf16x8 o;
#pragma unroll
      for (int q = 0; q < 4; ++q) { o[q] = f2bf(u0[q]); o[q + 4] = f2bf(u1[q]); }
      *(bf16x8*)(smem + ao + c * 16) = o;
    }
  };

  const int t0 = blockIdx.x;
  if (t0 >= ntiles) return;
  int sb = 0, acur = 0;

  // prologue: A(tile0) + W1 slices 0,1 -> full drain once
  if (A_BF16) stageA(t0, LDS_A0); else stageA_f32(t0, LDS_A0);
  stageW(W1t, 0, 0);
  stageW(W1t, 1, 16384);
  asm volatile("s_waitcnt vmcnt(0) lgkmcnt(0)" ::: "memory");
  SBAR();

  for (int t = t0; t < ntiles; t += gridDim.x) {
    const int r0 = t * 64;
    const int so0 = sb * 16384;
    const int so1 = ((sb + 1) % 3) * 16384;
    const int so2 = ((sb + 2) % 3) * 16384;
    const int aoC = acur ? LDS_A1 : LDS_A0;
    const int aoN = acur ? LDS_A0 : LDS_A1;
    const bool hn = (t + (int)gridDim.x) < ntiles;

    f32x4 acc[2][4];
#pragma unroll
    for (int mi = 0; mi < 2; ++mi)
#pragma unroll
      for (int ni = 0; ni < 4; ++ni) acc[mi][ni] = (f32x4){0.f, 0.f, 0.f, 0.f};

    // ---------------- GEMM1: steps 0..7 ----------------
#pragma unroll
    for (int s = 0; s < 8; ++s) {
      const int soR = (s % 3 == 0) ? so0 : (s % 3 == 1) ? so1 : so2;  // (sb+s)%3
      const int soS = (s % 3 == 0) ? so2 : (s % 3 == 1) ? so0 : so1;  // (sb+s+2)%3
      if (s < 6) stageW(W1t, s + 2, soS);
      else       stageW(W2t, s - 6, soS);
      bf16x8 a[2], b[4];
#pragma unroll
      for (int mi = 0; mi < 2; ++mi) {
        const int row = wm * 32 + mi * 16 + l15;
        const int ks = (s * 4 + lq) ^ (row & 31);
        a[mi] = *(const bf16x8*)(smem + aoC + (row * 32 + ks) * 16);
      }
#pragma unroll
      for (int ni = 0; ni < 4; ++ni)
        b[ni] = *(const bf16x8*)(smem + soR + lq * 4096 + (cbase + ni * 16 + l15) * 16);
#pragma unroll
      for (int ni = 0; ni < 4; ++ni)
#pragma unroll
        for (int mi = 0; mi < 2; ++mi)
          acc[mi][ni] = __builtin_amdgcn_mfma_f32_16x16x32_bf16(a[mi], b[ni], acc[mi][ni], 0, 0, 0);
      asm volatile("s_waitcnt vmcnt(2)" ::: "memory");
      SBAR();
    }

    // ---- EPI1: bias+relu -> hidden (aliases A[cur]; granule swizzle) ----
    short* hid = (short*)(smem + aoC);
#pragma unroll
    for (int ni = 0; ni < 4; ++ni) {
      const int c = cbase + ni * 16 + l15;
#pragma unroll
      for (int mi = 0; mi < 2; ++mi)
#pragma unroll
        for (int i = 0; i < 4; ++i) {
          const int row = wm * 32 + mi * 16 + lq * 4 + i;
          hid[row * DD + ((((c >> 3) ^ (row & 7))) << 3) + (c & 7)] =
              f2bf(fmaxf(acc[mi][ni][i] + b1v[ni], 0.f));
          acc[mi][ni][i] = 0.f;
        }
    }
    asm volatile("s_waitcnt lgkmcnt(0)" ::: "memory");
    SBAR();

    // ---------------- GEMM2: steps 8..15 (u=0..7) ----------------
#pragma unroll
    for (int u = 0; u < 8; ++u) {
      const int soR = (u % 3 == 0) ? so2 : (u % 3 == 1) ? so0 : so1;  // (sb+u+8)%3
      const int soS = (u % 3 == 0) ? so1 : (u % 3 == 1) ? so2 : so0;  // (sb+u+10)%3
      if (u < 6) stageW(W2t, u + 2, soS);
      else       stageW(W1t, u - 6, soS);  // next tile's W1 slices 0,1 (same W1)
      if (u == 0 && A_BF16 && hn) {
        __builtin_amdgcn_sched_barrier(0);  // pin W-before-A issue order
        stageA(t + gridDim.x, aoN);
        __builtin_amdgcn_sched_barrier(0);
      }
      bf16x8 a[2], b[4];
#pragma unroll
      for (int mi = 0; mi < 2; ++mi) {
        const int row = wm * 32 + mi * 16 + l15;
        a[mi] = *(const bf16x8*)(hid + row * DD + (((u * 4 + lq) ^ (row & 7)) << 3));
      }
#pragma unroll
      for (int ni = 0; ni < 4; ++ni)
        b[ni] = *(const bf16x8*)(smem + soR + lq * 4096 + (cbase + ni * 16 + l15) * 16);
#pragma unroll
      for (int ni = 0; ni < 4; ++ni)
#pragma unroll
        for (int mi = 0; mi < 2; ++mi)
          acc[mi][ni] = __builtin_amdgcn_mfma_f32_16x16x32_bf16(a[mi], b[ni], acc[mi][ni], 0, 0, 0);
      if (u <= 1) {
        if (A_BF16 && hn) asm volatile("s_waitcnt vmcnt(6)" ::: "memory");
        else              asm volatile("s_waitcnt vmcnt(2)" ::: "memory");
      } else if (u < 7) {
        asm volatile("s_waitcnt vmcnt(2)" ::: "memory");
      } else {
        asm volatile("s_waitcnt lgkmcnt(0)" ::: "memory");
      }
      SBAR();
    }

    // ---------------- LN ----------------
    float mean_[2][4], inv_[2][4];
#pragma unroll
    for (int mi = 0; mi < 2; ++mi)
#pragma unroll
      for (int i = 0; i < 4; ++i) {
        float s1 = 0.f, s2 = 0.f;
#pragma unroll
        for (int ni = 0; ni < 4; ++ni) {
          const float v = acc[mi][ni][i] + b2v[ni];
          s1 += v; s2 += v * v;
        }
#pragma unroll
        for (int off = 1; off < 16; off <<= 1) {
          s1 += __shfl_xor(s1, off);
          s2 += __shfl_xor(s2, off);
        }
        mean_[mi][i] = s1; inv_[mi][i] = s2;
      }
    if (l15 == 0) {
#pragma unroll
      for (int mi = 0; mi < 2; ++mi)
#pragma unroll
        for (int i = 0; i < 4; ++i) {
          const int row = wm * 32 + mi * 16 + lq * 4 + i;
          redbuf[(row * 4 + wn) * 2 + 0] = mean_[mi][i];
          redbuf[(row * 4 + wn) * 2 + 1] = inv_[mi][i];
        }
    }
    asm volatile("s_waitcnt lgkmcnt(0)" ::: "memory");
    SBAR();
#pragma unroll
    for (int mi = 0; mi < 2; ++mi)
#pragma unroll
      for (int i = 0; i < 4; ++i) {
        const int row = wm * 32 + mi * 16 + lq * 4 + i;
        float t1 = 0.f, t2 = 0.f;
#pragma unroll
        for (int w = 0; w < 4; ++w) {
          t1 += redbuf[(row * 4 + w) * 2 + 0];
          t2 += redbuf[(row * 4 + w) * 2 + 1];
        }
        const float mean = t1 * (1.f / 256.f);
        const float var = t2 * (1.f / 256.f) - mean * mean;
        mean_[mi][i] = mean;
        inv_[mi][i] = rsqrtf(var + LN_EPS);
      }
    asm volatile("s_waitcnt lgkmcnt(0)" ::: "memory");
    SBAR();  // redbuf reads done; hidden region reusable

    // ---------------- EPI2: output via A[cur] region ----------------
    if (NODE) {
      float* ob = (float*)(smem + aoC);
#pragma unroll
      for (int h = 0; h < 2; ++h) {
        if ((cbase >> 7) == h) {
#pragma unroll
          for (int ni = 0; ni < 4; ++ni) {
            const int cl = cbase - h * 128 + ni * 16 + l15;
#pragma unroll
            for (int mi = 0; mi < 2; ++mi)
#pragma unroll
              for (int i = 0; i < 4; ++i) {
                const int row = wm * 32 + mi * 16 + lq * 4 + i;
                const float y = (acc[mi][ni][i] + b2v[ni] - mean_[mi][i]) * inv_[mi][i] * gv[ni] + bvv[ni];
                ob[row * 128 + (((cl >> 2) ^ (row & 7)) << 2) + (cl & 3)] = y;
              }
          }
        }
        asm volatile("s_waitcnt lgkmcnt(0)" ::: "memory");
        SBAR();
#pragma unroll
        for (int j = 0; j < 4; ++j) {
          const int gg = tid + 512 * j;
          const int row = gg >> 5, Lc = gg & 31;
          const int grow = r0 + row;
          if (grow < M) {
            f32x4 v = *(const f32x4*)(ob + row * 128 + ((Lc ^ (row & 7)) << 2));
            const f32x4 xr = *(const f32x4*)(Resid + (size_t)grow * DD + h * 128 + Lc * 4);
            v = v + xr;
            *(f32x4*)(OutF + (size_t)grow * DD + h * 128 + Lc * 4) = v;
            s16x4 o; o.x = f2bf(v.x); o.y = f2bf(v.y); o.z = f2bf(v.z); o.w = f2bf(v.w);
            *(s16x4*)(XbOut + (size_t)grow * DD + h * 128 + Lc * 4) = o;
          }
        }
        if (h == 0) { asm volatile("s_waitcnt lgkmcnt(0)" ::: "memory"); SBAR(); }
      }
    } else {
      short* ob = (short*)(smem + aoC);
#pragma unroll
      for (int ni = 0; ni < 4; ++ni) {
        const int c = cbase + ni * 16 + l15;
#pragma unroll
        for (int mi = 0; mi < 2; ++mi)
#pragma unroll
          for (int i = 0; i < 4; ++i) {
            const int row = wm * 32 + mi * 16 + lq * 4 + i;
            const float y = (acc[mi][ni][i] + b2v[ni] - mean_[mi][i]) * inv_[mi][i] * gv[ni] + bvv[ni];
            ob[row * DD + (((c >> 3) ^ (row & 7)) << 3) + (c & 7)] = f2bf(y);
          }
      }
      asm volatile("s_waitcnt lgkmcnt(0)" ::: "memory");
      SBAR();
#pragma unroll
      for (int j = 0; j < 4; ++j) {
        const int gg = tid + 512 * j;
        const int row = gg >> 5, Lg = gg & 31;
        const int grow = r0 + row;
        if (grow < M) {
          const i32x4 v = *(const i32x4*)(ob + row * DD + ((Lg ^ (row & 7)) << 3));
          *(i32x4*)(OutB + (size_t)grow * DD + Lg * 8) = v;
        }
      }
    }
    if (!A_BF16 && hn) stageA_f32(t + gridDim.x, aoN);  // fallback path
    // tile-boundary drain (once per 16 steps): covers stores + in-flight W/A
    asm volatile("s_waitcnt vmcnt(0) lgkmcnt(0)" ::: "memory");
    SBAR();
    acur ^= 1;
    sb = (sb == 2) ? 0 : sb + 1;
  }
}

// ----------------------- aggregation: wave per node, CSR-sorted efeat ------
__global__ __launch_bounds__(256) void aggregate_kernel(
    const short* __restrict__ xb, const short* __restrict__ efs,
    const int* __restrict__ offs, const int* __restrict__ ssrc,
    short* __restrict__ aggr) {
  const int w = (blockIdx.x * blockDim.x + threadIdx.x) >> 6;
  if (w >= NNODE) return;
  const int lane = threadIdx.x & 63;
  const int beg = offs[w], end = offs[w + 1];
  float s0 = 0.f, s1 = 0.f, s2 = 0.f, s3 = 0.f;
  int p = beg;
  for (; p + 3 < end; p += 4) {
    const int a0 = ssrc[p], a1 = ssrc[p + 1], a2 = ssrc[p + 2], a3 = ssrc[p + 3];
    const s16x4 e0 = *(const s16x4*)(efs + (size_t)p * DD + lane * 4);
    const s16x4 e1 = *(const s16x4*)(efs + (size_t)(p + 1) * DD + lane * 4);
    const s16x4 e2 = *(const s16x4*)(efs + (size_t)(p + 2) * DD + lane * 4);
    const s16x4 e3 = *(const s16x4*)(efs + (size_t)(p + 3) * DD + lane * 4);
    const s16x4 x0 = *(const s16x4*)(xb + (size_t)a0 * DD + lane * 4);
    const s16x4 x1 = *(const s16x4*)(xb + (size_t)a1 * DD + lane * 4);
    const s16x4 x2 = *(const s16x4*)(xb + (size_t)a2 * DD + lane * 4);
    const s16x4 x3 = *(const s16x4*)(xb + (size_t)a3 * DD + lane * 4);
    s0 += bf2f(e0.x) + bf2f(x0.x) + bf2f(e1.x) + bf2f(x1.x) +
          bf2f(e2.x) + bf2f(x2.x) + bf2f(e3.x) + bf2f(x3.x);
    s1 += bf2f(e0.y) + bf2f(x0.y) + bf2f(e1.y) + bf2f(x1.y) +
          bf2f(e2.y) + bf2f(x2.y) + bf2f(e3.y) + bf2f(x3.y);
    s2 += bf2f(e0.z) + bf2f(x0.z) + bf2f(e1.z) + bf2f(x1.z) +
          bf2f(e2.z) + bf2f(x2.z) + bf2f(e3.z) + bf2f(x3.z);
    s3 += bf2f(e0.w) + bf2f(x0.w) + bf2f(e1.w) + bf2f(x1.w) +
          bf2f(e2.w) + bf2f(x2.w) + bf2f(e3.w) + bf2f(x3.w);
  }
  for (; p < end; ++p) {
    const s16x4 ev = *(const s16x4*)(efs + (size_t)p * DD + lane * 4);
    const s16x4 xv = *(const s16x4*)(xb + (size_t)ssrc[p] * DD + lane * 4);
    s0 += bf2f(ev.x) + bf2f(xv.x);
    s1 += bf2f(ev.y) + bf2f(xv.y);
    s2 += bf2f(ev.z) + bf2f(xv.z);
    s3 += bf2f(ev.w) + bf2f(xv.w);
  }
  s16x4 o; o.x = f2bf(s0); o.y = f2bf(s1); o.z = f2bf(s2); o.w = f2bf(s3);
  *(s16x4*)(aggr + (size_t)w * DD + lane * 4) = o;
}

__global__ void count_kernel(const int* __restrict__ tgt, int* __restrict__ deg) {
  const int e = blockIdx.x * 256 + threadIdx.x;
  if (e < NEDGE) atomicAdd(&deg[tgt[e]], 1);
}

// ---------- 3-stage multi-block exclusive scan (replaces 265us 1-block scan)
__global__ __launch_bounds__(256) void scan1_kernel(
    const int* __restrict__ deg, int* __restrict__ locex, int* __restrict__ bsum) {
  __shared__ int sh[256];
  const int t = threadIdx.x, b = blockIdx.x;
  const int idx = b * 256 + t;
  const int v = (idx < NNODE) ? deg[idx] : 0;
  sh[t] = v;
  __syncthreads();
#pragma unroll
  for (int off = 1; off < 256; off <<= 1) {
    const int add = (t >= off) ? sh[t - off] : 0;
    __syncthreads();
    sh[t] += add;
    __syncthreads();
  }
  if (idx < NNODE) locex[idx] = sh[t] - v;
  if (t == 255) bsum[b] = sh[255];
}

__global__ __launch_bounds__(512) void scan2_kernel(int* __restrict__ bsum, int nb) {
  __shared__ int sh[512];
  const int t = threadIdx.x;
  const int v = (t < nb) ? bsum[t] : 0;
  sh[t] = v;
  __syncthreads();
#pragma unroll
  for (int off = 1; off < 512; off <<= 1) {
    const int add = (t >= off) ? sh[t - off] : 0;
    __syncthreads();
    sh[t] += add;
    __syncthreads();
  }
  if (t < nb) bsum[t] = sh[t] - v;
}

__global__ __launch_bounds__(256) void scan3_kernel(
    const int* __restrict__ locex, const int* __restrict__ bsum,
    int* __restrict__ offs, int* __restrict__ cur) {
  const int idx = blockIdx.x * 256 + threadIdx.x;
  if (idx < NNODE) {
    const int o = locex[idx] + bsum[blockIdx.x];
    offs[idx] = o;
    cur[idx] = o;
  }
  if (idx == 0) offs[NNODE] = NEDGE;
}

__global__ void fill_kernel(const int* __restrict__ src, const int* __restrict__ tgt,
                            int* cur, int* seid, int* ssrc) {
  const int e = blockIdx.x * 256 + threadIdx.x;
  if (e < NEDGE) {
    const int t = tgt[e];
    const int p = atomicAdd(&cur[t], 1);
    seid[p] = e;
    ssrc[p] = src[e];
  }
}

__global__ void cvt4_kernel(const float* __restrict__ src, short* __restrict__ dst, int n4) {
  for (int i = blockIdx.x * blockDim.x + threadIdx.x; i < n4; i += gridDim.x * blockDim.x) {
    const f32x4 v = ((const f32x4*)src)[i];
    s16x4 o;
    o.x = f2bf(v.x); o.y = f2bf(v.y); o.z = f2bf(v.z); o.w = f2bf(v.w);
    ((s16x4*)dst)[i] = o;
  }
}

__global__ __launch_bounds__(256) void gather_cvt_kernel(
    const float* __restrict__ src, const int* __restrict__ perm,
    short* __restrict__ dst, int n) {
  const int w = (blockIdx.x * blockDim.x + threadIdx.x) >> 6;
  if (w >= n) return;
  const int lane = threadIdx.x & 63;
  const f32x4 v = *(const f32x4*)(src + (size_t)perm[w] * DD + lane * 4);
  s16x4 o; o.x = f2bf(v.x); o.y = f2bf(v.y); o.z = f2bf(v.z); o.w = f2bf(v.w);
  *(s16x4*)(dst + (size_t)w * DD + lane * 4) = o;
}

// ---------------------------------------------------------------------------
extern "C" void kernel_launch(void* const* d_in, const int* in_sizes, int n_in,
                              void* d_out, int out_size, void* d_ws, size_t ws_size,
                              hipStream_t stream) {
  const float* x_in = (const float*)d_in[0];
  const float* ea_f = (const float*)d_in[1];
  const float* e1w = (const float*)d_in[2];
  const float* e1b = (const float*)d_in[3];
  const float* e2w = (const float*)d_in[4];
  const float* e2b = (const float*)d_in[5];
  const float* elg = (const float*)d_in[6];
  const float* elb = (const float*)d_in[7];
  const float* n1w = (const float*)d_in[8];
  const float* n1b = (const float*)d_in[9];
  const float* n2w = (const float*)d_in[10];
  const float* n2b = (const float*)d_in[11];
  const float* nlg = (const float*)d_in[12];
  const float* nlb = (const float*)d_in[13];
  const int* eidx = (const int*)d_in[14];
  float* x = (float*)d_out;

  char* p = (char*)d_ws;
  auto take = [&](size_t bytes) {
    char* r = p;
    p += (bytes + 255) & ~(size_t)255;
    return r;
  };
  short* efeat = (short*)take((size_t)NEDGE * DD * 2);
  short* aggr = (short*)take((size_t)NNODE * DD * 2);
  short* xb = (short*)take((size_t)NNODE * DD * 2);
  short* we1t = (short*)take((size_t)NLAY * DD * DD * 2);
  short* we2t = (short*)take((size_t)NLAY * DD * DD * 2);
  short* wn1t = (short*)take((size_t)NLAY * DD * DD * 2);
  short* wn2t = (short*)take((size_t)NLAY * DD * DD * 2);
  int* deg = (int*)take((size_t)NNODE * 4);
  int* offs = (int*)take((size_t)(NNODE + 1) * 4);
  int* cur = (int*)take((size_t)NNODE * 4);
  int* seid = (int*)take((size_t)NEDGE * 4);
  int* ssrc = (int*)take((size_t)NEDGE * 4);
  int* locex = (int*)take((size_t)(NNODE + 256) * 4);
  int* bsum = (int*)take(512 * 4);
  short* eab = (short*)take((size_t)NEDGE * DD * 2);
  const bool use_eab = ((size_t)(p - (char*)d_ws) <= ws_size);

  const int SMEM = LDS_TOTAL;
  hipFuncSetAttribute((const void*)mlp_kernel<true, false>,
                      hipFuncAttributeMaxDynamicSharedMemorySize, SMEM);
  hipFuncSetAttribute((const void*)mlp_kernel<false, false>,
                      hipFuncAttributeMaxDynamicSharedMemorySize, SMEM);
  hipFuncSetAttribute((const void*)mlp_kernel<true, true>,
                      hipFuncAttributeMaxDynamicSharedMemorySize, SMEM);

  hipMemcpyAsync(x, x_in, (size_t)NNODE * DD * 4, hipMemcpyDeviceToDevice, stream);

  cvtw_kernel<<<288, 256, 0, stream>>>(e1w, we1t, NLAY);
  cvtw_kernel<<<288, 256, 0, stream>>>(e2w, we2t, NLAY);
  cvtw_kernel<<<288, 256, 0, stream>>>(n1w, wn1t, NLAY);
  cvtw_kernel<<<288, 256, 0, stream>>>(n2w, wn2t, NLAY);
  cvt4_kernel<<<2048, 256, 0, stream>>>(x_in, xb, NNODE * DD / 4);

  const int NB = (NNODE + 255) / 256;  // 391
  hipMemsetAsync(deg, 0, (size_t)NNODE * 4, stream);
  count_kernel<<<(NEDGE + 255) / 256, 256, 0, stream>>>(eidx + NEDGE, deg);
  scan1_kernel<<<NB, 256, 0, stream>>>(deg, locex, bsum);
  scan2_kernel<<<1, 512, 0, stream>>>(bsum, NB);
  scan3_kernel<<<NB, 256, 0, stream>>>(locex, bsum, offs, cur);
  fill_kernel<<<(NEDGE + 255) / 256, 256, 0, stream>>>(eidx, eidx + NEDGE, cur, seid, ssrc);
  if (use_eab)
    gather_cvt_kernel<<<NEDGE / 4, 256, 0, stream>>>(ea_f, seid, eab, NEDGE);

  for (int l = 0; l < NLAY; ++l) {
    if (use_eab) {
      mlp_kernel<true, false><<<256, 512, SMEM, stream>>>(
          eab, nullptr, we1t + l * 65536, we2t + l * 65536, e1b + l * DD,
          e2b + l * DD, elg + l * DD, elb + l * DD, efeat, nullptr, nullptr,
          nullptr, NEDGE);
    } else {
      mlp_kernel<false, false><<<256, 512, SMEM, stream>>>(
          ea_f, seid, we1t + l * 65536, we2t + l * 65536, e1b + l * DD,
          e2b + l * DD, elg + l * DD, elb + l * DD, efeat, nullptr, nullptr,
          nullptr, NEDGE);
    }
    aggregate_kernel<<<(NNODE * 64 + 255) / 256, 256, 0, stream>>>(xb, efeat, offs, ssrc, aggr);
    mlp_kernel<true, true><<<256, 512, SMEM, stream>>>(
        aggr, nullptr, wn1t + l * 65536, wn2t + l * 65536, n1b + l * DD,
        n2b + l * DD, nlg + l * DD, nlb + l * DD, nullptr, x, x, xb, NNODE);
  }
  (void)in_sizes; (void)n_in; (void)out_size; (void)ws_size;
}

// Round 10
// 3269.044 us; speedup vs baseline: 1.7739x; 1.7739x over previous
//
#include <hip/hip_runtime.h>
#include <stdint.h>

#define DD 256
#define NEDGE 300000
#define NNODE 100000
#define NLAY 9
#define LN_EPS 1e-5f

typedef __attribute__((ext_vector_type(8))) short bf16x8;
typedef __attribute__((ext_vector_type(4))) short s16x4;
typedef __attribute__((ext_vector_type(4))) float f32x4;
typedef __attribute__((ext_vector_type(4))) int i32x4;

static __device__ __forceinline__ short f2bf(float f) {
  union { float f; uint32_t u; } v; v.f = f;
  uint32_t r = (v.u + 0x7FFFu + ((v.u >> 16) & 1u)) >> 16;
  return (short)(uint16_t)r;
}
static __device__ __forceinline__ float bf2f(short s) {
  union { uint32_t u; float f; } v; v.u = ((uint32_t)(uint16_t)s) << 16;
  return v.f;
}

static __device__ __forceinline__ void gld16(const void* g, void* l) {
  __builtin_amdgcn_global_load_lds((const __attribute__((address_space(1))) void*)g,
                                   (__attribute__((address_space(3))) void*)l, 16, 0, 0);
}

// ---------------------------------------------------------------------------
// Weight pre-transpose + bf16: global chunk j (16B) = kq*256+col holds
// W[col][kq*8..kq*8+7]; K-slice s (32 k) = chunks [s*1024, (s+1)*1024).
// ---------------------------------------------------------------------------
__global__ void cvtw_kernel(const float* __restrict__ src, short* __restrict__ dst, int nmat) {
  const int total = nmat * 8192;
  for (int j = blockIdx.x * blockDim.x + threadIdx.x; j < total; j += gridDim.x * blockDim.x) {
    const int m = j >> 13;
    const int jj = j & 8191;
    const int col = jj & 255;
    const int kq = jj >> 8;
    const float* s = src + (size_t)m * 65536 + col * 256 + kq * 8;
    const f32x4 u0 = *(const f32x4*)(s);
    const f32x4 u1 = *(const f32x4*)(s + 4);
    bf16x8 o;
#pragma unroll
    for (int q = 0; q < 4; ++q) { o[q] = f2bf(u0[q]); o[q + 4] = f2bf(u1[q]); }
    *(bf16x8*)(dst + (size_t)j * 8) = o;
  }
}

// ---------------------------------------------------------------------------
// Fused MLP v10 — R7 schedule, 16-waves/CU geometry.
// 512 thr = 8 waves (2M x 4N); tile 64r x 256c; wave 32r x 64c; acc[2][4].
// A staged ONCE per tile (32KB, [kq][row][16B], conflict-free); per K-step
// stage = one 16KB W slice via global_load_lds into 2-slot dbuf; ONE
// __syncthreads per K-step (compiler manages waitcnts — no inline asm).
// A region aliases hidden after GEMM1 and the output buffer after LN.
// LDS: Wslot0 @0, Wslot1 @16384, A/hidden @32768 (32KB), red @65536 (2KB).
// Total 67584 -> 2 blocks/CU x 8 waves = 16 waves/CU.
// ---------------------------------------------------------------------------
template<bool A_BF16, bool NODE>
__global__ __launch_bounds__(512, 4) void mlp_kernel(
    const void* __restrict__ Ain, const int* __restrict__ rowmap,
    const short* __restrict__ W1t, const short* __restrict__ W2t,
    const float* __restrict__ B1, const float* __restrict__ B2,
    const float* __restrict__ LG, const float* __restrict__ LB,
    short* __restrict__ OutB, float* __restrict__ OutF,
    const float* __restrict__ Resid, short* __restrict__ XbOut, int M) {
  extern __shared__ char smem[];
  char* Abuf = smem + 32768;
  float* redbuf = (float*)(smem + 65536);
  const int tid = threadIdx.x;
  const int lane = tid & 63;
  const int wv = tid >> 6;
  const int wm = wv >> 2, wn = wv & 3;
  const int l15 = lane & 15, lq = lane >> 4;
  const int cbase = wn * 64;
  const int r0 = blockIdx.x * 64;

  // stage one 16KB W slice (1024 chunks); lanes contiguous, wave-uniform dest
  auto stageW = [&](const short* Wt, int s, int slot) {
#pragma unroll
    for (int j = 0; j < 2; ++j) {
      const int c = tid + 512 * j;
      gld16(Wt + ((size_t)s * 1024 + c) * 8, smem + slot * 16384 + c * 16);
    }
  };

  // ---- stage whole A tile: 2048 chunks, c=(kq*64+row), kq=w+8j uniform ----
  if (A_BF16) {
    const short* A = (const short*)Ain;
#pragma unroll
    for (int j = 0; j < 4; ++j) {
      const int c = tid + 512 * j;
      const int row = c & 63, kq = c >> 6;
      const int gr = min(r0 + row, M - 1);
      gld16(A + (size_t)gr * DD + kq * 8, Abuf + c * 16);
    }
  } else {
    const float* A = (const float*)Ain;
#pragma unroll
    for (int j = 0; j < 4; ++j) {
      const int c = tid + 512 * j;
      const int row = c & 63, kq = c >> 6;
      const int gr0 = min(r0 + row, M - 1);
      const int gr = rowmap ? rowmap[gr0] : gr0;
      const f32x4 u0 = *(const f32x4*)(A + (size_t)gr * DD + kq * 8);
      const f32x4 u1 = *(const f32x4*)(A + (size_t)gr * DD + kq * 8 + 4);
      bf16x8 o;
#pragma unroll
      for (int q = 0; q < 4; ++q) { o[q] = f2bf(u0[q]); o[q + 4] = f2bf(u1[q]); }
      *(bf16x8*)(Abuf + c * 16) = o;
    }
  }
  stageW(W1t, 0, 0);
  __syncthreads();  // A + W1 slice0 ready

  f32x4 acc[2][4];
#pragma unroll
  for (int mi = 0; mi < 2; ++mi)
#pragma unroll
    for (int ni = 0; ni < 4; ++ni) acc[mi][ni] = (f32x4){0.f, 0.f, 0.f, 0.f};

  // ---------------- GEMM1: h = relu(A @ W1^T + b1) -------------------------
#pragma unroll
  for (int s = 0; s < 8; ++s) {
    if (s < 7) stageW(W1t, s + 1, (s + 1) & 1);
    else       stageW(W2t, 0, 0);  // slot0 last read at s=6
    const char* wb = smem + (s & 1) * 16384;
    bf16x8 a[2], b[4];
#pragma unroll
    for (int mi = 0; mi < 2; ++mi)
      a[mi] = *(const bf16x8*)(Abuf + (((s * 4 + lq) * 64) + wm * 32 + mi * 16 + l15) * 16);
#pragma unroll
    for (int ni = 0; ni < 4; ++ni)
      b[ni] = *(const bf16x8*)(wb + lq * 4096 + (cbase + ni * 16 + l15) * 16);
#pragma unroll
    for (int ni = 0; ni < 4; ++ni)
#pragma unroll
      for (int mi = 0; mi < 2; ++mi)
        acc[mi][ni] = __builtin_amdgcn_mfma_f32_16x16x32_bf16(a[mi], b[ni], acc[mi][ni], 0, 0, 0);
    __syncthreads();  // publish staged slot; guard slot reuse
  }

  // ---- EPI1: bias+relu -> hidden (aliases Abuf; granule-swizzled) ---------
  short* hid = (short*)Abuf;
  {
    float b1v[4];
#pragma unroll
    for (int ni = 0; ni < 4; ++ni) b1v[ni] = B1[cbase + ni * 16 + l15];
#pragma unroll
    for (int ni = 0; ni < 4; ++ni) {
      const int c = cbase + ni * 16 + l15;
#pragma unroll
      for (int mi = 0; mi < 2; ++mi)
#pragma unroll
        for (int i = 0; i < 4; ++i) {
          const int row = wm * 32 + mi * 16 + lq * 4 + i;
          hid[row * DD + ((((c >> 3) ^ (row & 7))) << 3) + (c & 7)] =
              f2bf(fmaxf(acc[mi][ni][i] + b1v[ni], 0.f));
          acc[mi][ni][i] = 0.f;
        }
    }
  }
  __syncthreads();  // hidden ready; W2 slice0 (staged at s=7) drained

  // ---------------- GEMM2: y = h @ W2^T ------------------------------------
#pragma unroll
  for (int s = 0; s < 8; ++s) {
    if (s < 7) stageW(W2t, s + 1, (s + 1) & 1);
    const char* wb = smem + (s & 1) * 16384;
    bf16x8 a[2], b[4];
#pragma unroll
    for (int mi = 0; mi < 2; ++mi) {
      const int row = wm * 32 + mi * 16 + l15;
      a[mi] = *(const bf16x8*)(hid + row * DD + (((s * 4 + lq) ^ (row & 7)) << 3));
    }
#pragma unroll
    for (int ni = 0; ni < 4; ++ni)
      b[ni] = *(const bf16x8*)(wb + lq * 4096 + (cbase + ni * 16 + l15) * 16);
#pragma unroll
    for (int ni = 0; ni < 4; ++ni)
#pragma unroll
      for (int mi = 0; mi < 2; ++mi)
        acc[mi][ni] = __builtin_amdgcn_mfma_f32_16x16x32_bf16(a[mi], b[ni], acc[mi][ni], 0, 0, 0);
    __syncthreads();
  }

  // ---------------- LN ----------------
  float b2v[4], gv[4], bvv[4];
#pragma unroll
  for (int ni = 0; ni < 4; ++ni) {
    const int c = cbase + ni * 16 + l15;
    b2v[ni] = B2[c]; gv[ni] = LG[c]; bvv[ni] = LB[c];
  }
  float mean_[2][4], inv_[2][4];
#pragma unroll
  for (int mi = 0; mi < 2; ++mi)
#pragma unroll
    for (int i = 0; i < 4; ++i) {
      float s1 = 0.f, s2 = 0.f;
#pragma unroll
      for (int ni = 0; ni < 4; ++ni) {
        const float v = acc[mi][ni][i] + b2v[ni];
        s1 += v; s2 += v * v;
      }
#pragma unroll
      for (int off = 1; off < 16; off <<= 1) {
        s1 += __shfl_xor(s1, off);
        s2 += __shfl_xor(s2, off);
      }
      mean_[mi][i] = s1; inv_[mi][i] = s2;
    }
  if (l15 == 0) {
#pragma unroll
    for (int mi = 0; mi < 2; ++mi)
#pragma unroll
      for (int i = 0; i < 4; ++i) {
        const int row = wm * 32 + mi * 16 + lq * 4 + i;
        redbuf[(row * 4 + wn) * 2 + 0] = mean_[mi][i];
        redbuf[(row * 4 + wn) * 2 + 1] = inv_[mi][i];
      }
  }
  __syncthreads();  // redbuf ready; hidden reads complete
#pragma unroll
  for (int mi = 0; mi < 2; ++mi)
#pragma unroll
    for (int i = 0; i < 4; ++i) {
      const int row = wm * 32 + mi * 16 + lq * 4 + i;
      float t1 = 0.f, t2 = 0.f;
#pragma unroll
      for (int w = 0; w < 4; ++w) {
        t1 += redbuf[(row * 4 + w) * 2 + 0];
        t2 += redbuf[(row * 4 + w) * 2 + 1];
      }
      const float mean = t1 * (1.f / 256.f);
      const float var = t2 * (1.f / 256.f) - mean * mean;
      mean_[mi][i] = mean;
      inv_[mi][i] = rsqrtf(var + LN_EPS);
    }
  __syncthreads();  // redbuf consumed; A/hidden region free for output

  if (NODE) {
    float* ob = (float*)Abuf;  // 64 x 128 f32 per pass (32KB)
#pragma unroll
    for (int h = 0; h < 2; ++h) {
      if ((cbase >> 7) == h) {
#pragma unroll
        for (int ni = 0; ni < 4; ++ni) {
          const int cl = cbase - h * 128 + ni * 16 + l15;
#pragma unroll
          for (int mi = 0; mi < 2; ++mi)
#pragma unroll
            for (int i = 0; i < 4; ++i) {
              const int row = wm * 32 + mi * 16 + lq * 4 + i;
              const float y = (acc[mi][ni][i] + b2v[ni] - mean_[mi][i]) * inv_[mi][i] * gv[ni] + bvv[ni];
              ob[row * 128 + (((cl >> 2) ^ (row & 7)) << 2) + (cl & 3)] = y;
            }
        }
      }
      __syncthreads();  // ob(h) ready
#pragma unroll
      for (int j = 0; j < 4; ++j) {
        const int gg = tid + 512 * j;
        const int row = gg >> 5, Lc = gg & 31;
        const int grow = r0 + row;
        if (grow < M) {
          f32x4 v = *(const f32x4*)(ob + row * 128 + ((Lc ^ (row & 7)) << 2));
          const f32x4 xr = *(const f32x4*)(Resid + (size_t)grow * DD + h * 128 + Lc * 4);
          v = v + xr;
          *(f32x4*)(OutF + (size_t)grow * DD + h * 128 + Lc * 4) = v;
          s16x4 o; o.x = f2bf(v.x); o.y = f2bf(v.y); o.z = f2bf(v.z); o.w = f2bf(v.w);
          *(s16x4*)(XbOut + (size_t)grow * DD + h * 128 + Lc * 4) = o;
        }
      }
      if (h == 0) __syncthreads();  // pass-0 reads done before pass-1 writes
    }
  } else {
    short* ob = (short*)Abuf;  // 64 x 256 bf16 (32KB)
#pragma unroll
    for (int ni = 0; ni < 4; ++ni) {
      const int c = cbase + ni * 16 + l15;
#pragma unroll
      for (int mi = 0; mi < 2; ++mi)
#pragma unroll
        for (int i = 0; i < 4; ++i) {
          const int row = wm * 32 + mi * 16 + lq * 4 + i;
          const float y = (acc[mi][ni][i] + b2v[ni] - mean_[mi][i]) * inv_[mi][i] * gv[ni] + bvv[ni];
          ob[row * DD + (((c >> 3) ^ (row & 7)) << 3) + (c & 7)] = f2bf(y);
        }
    }
    __syncthreads();  // ob ready
#pragma unroll
    for (int j = 0; j < 4; ++j) {
      const int gg = tid + 512 * j;
      const int row = gg >> 5, Lg = gg & 31;
      const int grow = r0 + row;
      if (grow < M) {
        const i32x4 v = *(const i32x4*)(ob + row * DD + ((Lg ^ (row & 7)) << 3));
        *(i32x4*)(OutB + (size_t)grow * DD + Lg * 8) = v;
      }
    }
  }
}

// ----------------------- aggregation: wave per node, CSR-sorted efeat ------
__global__ __launch_bounds__(256) void aggregate_kernel(
    const short* __restrict__ xb, const short* __restrict__ efs,
    const int* __restrict__ offs, const int* __restrict__ ssrc,
    short* __restrict__ aggr) {
  const int w = (blockIdx.x * blockDim.x + threadIdx.x) >> 6;
  if (w >= NNODE) return;
  const int lane = threadIdx.x & 63;
  const int beg = offs[w], end = offs[w + 1];
  float s0 = 0.f, s1 = 0.f, s2 = 0.f, s3 = 0.f;
  int p = beg;
  for (; p + 3 < end; p += 4) {
    const int a0 = ssrc[p], a1 = ssrc[p + 1], a2 = ssrc[p + 2], a3 = ssrc[p + 3];
    const s16x4 e0 = *(const s16x4*)(efs + (size_t)p * DD + lane * 4);
    const s16x4 e1 = *(const s16x4*)(efs + (size_t)(p + 1) * DD + lane * 4);
    const s16x4 e2 = *(const s16x4*)(efs + (size_t)(p + 2) * DD + lane * 4);
    const s16x4 e3 = *(const s16x4*)(efs + (size_t)(p + 3) * DD + lane * 4);
    const s16x4 x0 = *(const s16x4*)(xb + (size_t)a0 * DD + lane * 4);
    const s16x4 x1 = *(const s16x4*)(xb + (size_t)a1 * DD + lane * 4);
    const s16x4 x2 = *(const s16x4*)(xb + (size_t)a2 * DD + lane * 4);
    const s16x4 x3 = *(const s16x4*)(xb + (size_t)a3 * DD + lane * 4);
    s0 += bf2f(e0.x) + bf2f(x0.x) + bf2f(e1.x) + bf2f(x1.x) +
          bf2f(e2.x) + bf2f(x2.x) + bf2f(e3.x) + bf2f(x3.x);
    s1 += bf2f(e0.y) + bf2f(x0.y) + bf2f(e1.y) + bf2f(x1.y) +
          bf2f(e2.y) + bf2f(x2.y) + bf2f(e3.y) + bf2f(x3.y);
    s2 += bf2f(e0.z) + bf2f(x0.z) + bf2f(e1.z) + bf2f(x1.z) +
          bf2f(e2.z) + bf2f(x2.z) + bf2f(e3.z) + bf2f(x3.z);
    s3 += bf2f(e0.w) + bf2f(x0.w) + bf2f(e1.w) + bf2f(x1.w) +
          bf2f(e2.w) + bf2f(x2.w) + bf2f(e3.w) + bf2f(x3.w);
  }
  for (; p < end; ++p) {
    const s16x4 ev = *(const s16x4*)(efs + (size_t)p * DD + lane * 4);
    const s16x4 xv = *(const s16x4*)(xb + (size_t)ssrc[p] * DD + lane * 4);
    s0 += bf2f(ev.x) + bf2f(xv.x);
    s1 += bf2f(ev.y) + bf2f(xv.y);
    s2 += bf2f(ev.z) + bf2f(xv.z);
    s3 += bf2f(ev.w) + bf2f(xv.w);
  }
  s16x4 o; o.x = f2bf(s0); o.y = f2bf(s1); o.z = f2bf(s2); o.w = f2bf(s3);
  *(s16x4*)(aggr + (size_t)w * DD + lane * 4) = o;
}

__global__ void count_kernel(const int* __restrict__ tgt, int* __restrict__ deg) {
  const int e = blockIdx.x * 256 + threadIdx.x;
  if (e < NEDGE) atomicAdd(&deg[tgt[e]], 1);
}

// ---------- 3-stage multi-block exclusive scan ----------
__global__ __launch_bounds__(256) void scan1_kernel(
    const int* __restrict__ deg, int* __restrict__ locex, int* __restrict__ bsum) {
  __shared__ int sh[256];
  const int t = threadIdx.x, b = blockIdx.x;
  const int idx = b * 256 + t;
  const int v = (idx < NNODE) ? deg[idx] : 0;
  sh[t] = v;
  __syncthreads();
#pragma unroll
  for (int off = 1; off < 256; off <<= 1) {
    const int add = (t >= off) ? sh[t - off] : 0;
    __syncthreads();
    sh[t] += add;
    __syncthreads();
  }
  if (idx < NNODE) locex[idx] = sh[t] - v;
  if (t == 255) bsum[b] = sh[255];
}

__global__ __launch_bounds__(512) void scan2_kernel(int* __restrict__ bsum, int nb) {
  __shared__ int sh[512];
  const int t = threadIdx.x;
  const int v = (t < nb) ? bsum[t] : 0;
  sh[t] = v;
  __syncthreads();
#pragma unroll
  for (int off = 1; off < 512; off <<= 1) {
    const int add = (t >= off) ? sh[t - off] : 0;
    __syncthreads();
    sh[t] += add;
    __syncthreads();
  }
  if (t < nb) bsum[t] = sh[t] - v;
}

__global__ __launch_bounds__(256) void scan3_kernel(
    const int* __restrict__ locex, const int* __restrict__ bsum,
    int* __restrict__ offs, int* __restrict__ cur) {
  const int idx = blockIdx.x * 256 + threadIdx.x;
  if (idx < NNODE) {
    const int o = locex[idx] + bsum[blockIdx.x];
    offs[idx] = o;
    cur[idx] = o;
  }
  if (idx == 0) offs[NNODE] = NEDGE;
}

__global__ void fill_kernel(const int* __restrict__ src, const int* __restrict__ tgt,
                            int* cur, int* seid, int* ssrc) {
  const int e = blockIdx.x * 256 + threadIdx.x;
  if (e < NEDGE) {
    const int t = tgt[e];
    const int p = atomicAdd(&cur[t], 1);
    seid[p] = e;
    ssrc[p] = src[e];
  }
}

__global__ void cvt4_kernel(const float* __restrict__ src, short* __restrict__ dst, int n4) {
  for (int i = blockIdx.x * blockDim.x + threadIdx.x; i < n4; i += gridDim.x * blockDim.x) {
    const f32x4 v = ((const f32x4*)src)[i];
    s16x4 o;
    o.x = f2bf(v.x); o.y = f2bf(v.y); o.z = f2bf(v.z); o.w = f2bf(v.w);
    ((s16x4*)dst)[i] = o;
  }
}

__global__ __launch_bounds__(256) void gather_cvt_kernel(
    const float* __restrict__ src, const int* __restrict__ perm,
    short* __restrict__ dst, int n) {
  const int w = (blockIdx.x * blockDim.x + threadIdx.x) >> 6;
  if (w >= n) return;
  const int lane = threadIdx.x & 63;
  const f32x4 v = *(const f32x4*)(src + (size_t)perm[w] * DD + lane * 4);
  s16x4 o; o.x = f2bf(v.x); o.y = f2bf(v.y); o.z = f2bf(v.z); o.w = f2bf(v.w);
  *(s16x4*)(dst + (size_t)w * DD + lane * 4) = o;
}

// ---------------------------------------------------------------------------
extern "C" void kernel_launch(void* const* d_in, const int* in_sizes, int n_in,
                              void* d_out, int out_size, void* d_ws, size_t ws_size,
                              hipStream_t stream) {
  const float* x_in = (const float*)d_in[0];
  const float* ea_f = (const float*)d_in[1];
  const float* e1w = (const float*)d_in[2];
  const float* e1b = (const float*)d_in[3];
  const float* e2w = (const float*)d_in[4];
  const float* e2b = (const float*)d_in[5];
  const float* elg = (const float*)d_in[6];
  const float* elb = (const float*)d_in[7];
  const float* n1w = (const float*)d_in[8];
  const float* n1b = (const float*)d_in[9];
  const float* n2w = (const float*)d_in[10];
  const float* n2b = (const float*)d_in[11];
  const float* nlg = (const float*)d_in[12];
  const float* nlb = (const float*)d_in[13];
  const int* eidx = (const int*)d_in[14];
  float* x = (float*)d_out;

  char* p = (char*)d_ws;
  auto take = [&](size_t bytes) {
    char* r = p;
    p += (bytes + 255) & ~(size_t)255;
    return r;
  };
  short* efeat = (short*)take((size_t)NEDGE * DD * 2);
  short* aggr = (short*)take((size_t)NNODE * DD * 2);
  short* xb = (short*)take((size_t)NNODE * DD * 2);
  short* we1t = (short*)take((size_t)NLAY * DD * DD * 2);
  short* we2t = (short*)take((size_t)NLAY * DD * DD * 2);
  short* wn1t = (short*)take((size_t)NLAY * DD * DD * 2);
  short* wn2t = (short*)take((size_t)NLAY * DD * DD * 2);
  int* deg = (int*)take((size_t)NNODE * 4);
  int* offs = (int*)take((size_t)(NNODE + 1) * 4);
  int* cur = (int*)take((size_t)NNODE * 4);
  int* seid = (int*)take((size_t)NEDGE * 4);
  int* ssrc = (int*)take((size_t)NEDGE * 4);
  int* locex = (int*)take((size_t)(NNODE + 256) * 4);
  int* bsum = (int*)take(512 * 4);
  short* eab = (short*)take((size_t)NEDGE * DD * 2);
  const bool use_eab = ((size_t)(p - (char*)d_ws) <= ws_size);

  const int SMEM = 67584;
  hipFuncSetAttribute((const void*)mlp_kernel<true, false>,
                      hipFuncAttributeMaxDynamicSharedMemorySize, SMEM);
  hipFuncSetAttribute((const void*)mlp_kernel<false, false>,
                      hipFuncAttributeMaxDynamicSharedMemorySize, SMEM);
  hipFuncSetAttribute((const void*)mlp_kernel<true, true>,
                      hipFuncAttributeMaxDynamicSharedMemorySize, SMEM);

  hipMemcpyAsync(x, x_in, (size_t)NNODE * DD * 4, hipMemcpyDeviceToDevice, stream);

  cvtw_kernel<<<288, 256, 0, stream>>>(e1w, we1t, NLAY);
  cvtw_kernel<<<288, 256, 0, stream>>>(e2w, we2t, NLAY);
  cvtw_kernel<<<288, 256, 0, stream>>>(n1w, wn1t, NLAY);
  cvtw_kernel<<<288, 256, 0, stream>>>(n2w, wn2t, NLAY);
  cvt4_kernel<<<2048, 256, 0, stream>>>(x_in, xb, NNODE * DD / 4);

  const int NB = (NNODE + 255) / 256;  // 391
  hipMemsetAsync(deg, 0, (size_t)NNODE * 4, stream);
  count_kernel<<<(NEDGE + 255) / 256, 256, 0, stream>>>(eidx + NEDGE, deg);
  scan1_kernel<<<NB, 256, 0, stream>>>(deg, locex, bsum);
  scan2_kernel<<<1, 512, 0, stream>>>(bsum, NB);
  scan3_kernel<<<NB, 256, 0, stream>>>(locex, bsum, offs, cur);
  fill_kernel<<<(NEDGE + 255) / 256, 256, 0, stream>>>(eidx, eidx + NEDGE, cur, seid, ssrc);
  if (use_eab)
    gather_cvt_kernel<<<NEDGE / 4, 256, 0, stream>>>(ea_f, seid, eab, NEDGE);

  const int egrid = (NEDGE + 63) / 64;
  const int ngrid = (NNODE + 63) / 64;
  for (int l = 0; l < NLAY; ++l) {
    if (use_eab) {
      mlp_kernel<true, false><<<egrid, 512, SMEM, stream>>>(
          eab, nullptr, we1t + l * 65536, we2t + l * 65536, e1b + l * DD,
          e2b + l * DD, elg + l * DD, elb + l * DD, efeat, nullptr, nullptr,
          nullptr, NEDGE);
    } else {
      mlp_kernel<false, false><<<egrid, 512, SMEM, stream>>>(
          ea_f, seid, we1t + l * 65536, we2t + l * 65536, e1b + l * DD,
          e2b + l * DD, elg + l * DD, elb + l * DD, efeat, nullptr, nullptr,
          nullptr, NEDGE);
    }
    aggregate_kernel<<<(NNODE * 64 + 255) / 256, 256, 0, stream>>>(xb, efeat, offs, ssrc, aggr);
    mlp_kernel<true, true><<<ngrid, 512, SMEM, stream>>>(
        aggr, nullptr, wn1t + l * 65536, wn2t + l * 65536, n1b + l * DD,
        n2b + l * DD, nlg + l * DD, nlb + l * DD, nullptr, x, x, xb, NNODE);
  }
  (void)in_sizes; (void)n_in; (void)out_size; (void)ws_size;
}

// Round 11
// 2972.554 us; speedup vs baseline: 1.9509x; 1.0997x over previous
//
#include <hip/hip_runtime.h>
#include <stdint.h>

#define DD 256
#define NEDGE 300000
#define NNODE 100000
#define NLAY 9
#define LN_EPS 1e-5f

typedef __attribute__((ext_vector_type(8))) short bf16x8;
typedef __attribute__((ext_vector_type(4))) short s16x4;
typedef __attribute__((ext_vector_type(4))) float f32x4;
typedef __attribute__((ext_vector_type(4))) int i32x4;

static __device__ __forceinline__ short f2bf(float f) {
  union { float f; uint32_t u; } v; v.f = f;
  uint32_t r = (v.u + 0x7FFFu + ((v.u >> 16) & 1u)) >> 16;
  return (short)(uint16_t)r;
}
static __device__ __forceinline__ float bf2f(short s) {
  union { uint32_t u; float f; } v; v.u = ((uint32_t)(uint16_t)s) << 16;
  return v.f;
}

static __device__ __forceinline__ void gld16(const void* g, void* l) {
  __builtin_amdgcn_global_load_lds((const __attribute__((address_space(1))) void*)g,
                                   (__attribute__((address_space(3))) void*)l, 16, 0, 0);
}

// ---------------------------------------------------------------------------
// Weight pre-transpose + bf16: global chunk j (16B) = kq*256+col holds
// W[col][kq*8..kq*8+7]; K-slice s (32 k) = chunks [s*1024, (s+1)*1024).
// ---------------------------------------------------------------------------
__global__ void cvtw_kernel(const float* __restrict__ src, short* __restrict__ dst, int nmat) {
  const int total = nmat * 8192;
  for (int j = blockIdx.x * blockDim.x + threadIdx.x; j < total; j += gridDim.x * blockDim.x) {
    const int m = j >> 13;
    const int jj = j & 8191;
    const int col = jj & 255;
    const int kq = jj >> 8;
    const float* s = src + (size_t)m * 65536 + col * 256 + kq * 8;
    const f32x4 u0 = *(const f32x4*)(s);
    const f32x4 u1 = *(const f32x4*)(s + 4);
    bf16x8 o;
#pragma unroll
    for (int q = 0; q < 4; ++q) { o[q] = f2bf(u0[q]); o[q + 4] = f2bf(u1[q]); }
    *(bf16x8*)(dst + (size_t)j * 8) = o;
  }
}

// ---------------------------------------------------------------------------
// Fused MLP v11 — swapped-operand MFMA (y^T in regs: lane=row, regs=4 cols).
// 512 thr = 8 waves (2M x 4N); tile 64r x 256c; wave 32r x 64c; acc[2][4].
// mfma(W_frag, A_frag, acc): identical fragment reads as v10 (A/B operand
// lane-structure is the same); epilogues become ds_write_b64 (4x fewer ops),
// LN reduces over regs + 2 shuffle stages. Staging/schedule = v10 verbatim.
// LDS: Wslot0 @0, Wslot1 @16384, A/hidden @32768 (32KB), red @65536 (2KB).
// ---------------------------------------------------------------------------
template<bool A_BF16, bool NODE>
__global__ __launch_bounds__(512, 4) void mlp_kernel(
    const void* __restrict__ Ain, const int* __restrict__ rowmap,
    const short* __restrict__ W1t, const short* __restrict__ W2t,
    const float* __restrict__ B1, const float* __restrict__ B2,
    const float* __restrict__ LG, const float* __restrict__ LB,
    short* __restrict__ OutB, float* __restrict__ OutF,
    const float* __restrict__ Resid, short* __restrict__ XbOut, int M) {
  extern __shared__ char smem[];
  char* Abuf = smem + 32768;
  float* redbuf = (float*)(smem + 65536);
  const int tid = threadIdx.x;
  const int lane = tid & 63;
  const int wv = tid >> 6;
  const int wm = wv >> 2, wn = wv & 3;
  const int l15 = lane & 15, lq = lane >> 4;
  const int cbase = wn * 64;
  const int r0 = blockIdx.x * 64;

  auto stageW = [&](const short* Wt, int s, int slot) {
#pragma unroll
    for (int j = 0; j < 2; ++j) {
      const int c = tid + 512 * j;
      gld16(Wt + ((size_t)s * 1024 + c) * 8, smem + slot * 16384 + c * 16);
    }
  };

  // ---- stage whole A tile: [kq][row][16B], conflict-free ----
  if (A_BF16) {
    const short* A = (const short*)Ain;
#pragma unroll
    for (int j = 0; j < 4; ++j) {
      const int c = tid + 512 * j;
      const int row = c & 63, kq = c >> 6;
      const int gr = min(r0 + row, M - 1);
      gld16(A + (size_t)gr * DD + kq * 8, Abuf + c * 16);
    }
  } else {
    const float* A = (const float*)Ain;
#pragma unroll
    for (int j = 0; j < 4; ++j) {
      const int c = tid + 512 * j;
      const int row = c & 63, kq = c >> 6;
      const int gr0 = min(r0 + row, M - 1);
      const int gr = rowmap ? rowmap[gr0] : gr0;
      const f32x4 u0 = *(const f32x4*)(A + (size_t)gr * DD + kq * 8);
      const f32x4 u1 = *(const f32x4*)(A + (size_t)gr * DD + kq * 8 + 4);
      bf16x8 o;
#pragma unroll
      for (int q = 0; q < 4; ++q) { o[q] = f2bf(u0[q]); o[q + 4] = f2bf(u1[q]); }
      *(bf16x8*)(Abuf + c * 16) = o;
    }
  }
  stageW(W1t, 0, 0);
  __syncthreads();  // A + W1 slice0 ready

  f32x4 acc[2][4];
#pragma unroll
  for (int mi = 0; mi < 2; ++mi)
#pragma unroll
    for (int ni = 0; ni < 4; ++ni) acc[mi][ni] = (f32x4){0.f, 0.f, 0.f, 0.f};

  // ---------------- GEMM1: h^T = (A @ W1^T)^T via mfma(W, A, acc) ----------
#pragma unroll
  for (int s = 0; s < 8; ++s) {
    if (s < 7) stageW(W1t, s + 1, (s + 1) & 1);
    else       stageW(W2t, 0, 0);
    const char* wb = smem + (s & 1) * 16384;
    bf16x8 a[2], b[4];
#pragma unroll
    for (int mi = 0; mi < 2; ++mi)
      a[mi] = *(const bf16x8*)(Abuf + (((s * 4 + lq) * 64) + wm * 32 + mi * 16 + l15) * 16);
#pragma unroll
    for (int ni = 0; ni < 4; ++ni)
      b[ni] = *(const bf16x8*)(wb + lq * 4096 + (cbase + ni * 16 + l15) * 16);
#pragma unroll
    for (int ni = 0; ni < 4; ++ni)
#pragma unroll
      for (int mi = 0; mi < 2; ++mi)
        acc[mi][ni] = __builtin_amdgcn_mfma_f32_16x16x32_bf16(b[ni], a[mi], acc[mi][ni], 0, 0, 0);
    __syncthreads();
  }

  // ---- EPI1: bias+relu -> hidden; thread holds 4 consecutive cols --------
  short* hid = (short*)Abuf;
  {
    f32x4 b1q[4];
#pragma unroll
    for (int ni = 0; ni < 4; ++ni)
      b1q[ni] = *(const f32x4*)(B1 + cbase + ni * 16 + lq * 4);
#pragma unroll
    for (int mi = 0; mi < 2; ++mi) {
      const int r = wm * 32 + mi * 16 + l15;
#pragma unroll
      for (int ni = 0; ni < 4; ++ni) {
        const int c4 = cbase + ni * 16 + lq * 4;
        s16x4 o;
#pragma unroll
        for (int i = 0; i < 4; ++i) {
          o[i] = f2bf(fmaxf(acc[mi][ni][i] + b1q[ni][i], 0.f));
          acc[mi][ni][i] = 0.f;
        }
        *(s16x4*)((char*)hid + r * 512 + (((c4 >> 3) ^ (r & 7)) << 4) + (c4 & 7) * 2) = o;
      }
    }
  }
  __syncthreads();  // hidden ready

  // ---------------- GEMM2: y^T = (h @ W2^T)^T ------------------------------
#pragma unroll
  for (int s = 0; s < 8; ++s) {
    if (s < 7) stageW(W2t, s + 1, (s + 1) & 1);
    const char* wb = smem + (s & 1) * 16384;
    bf16x8 a[2], b[4];
#pragma unroll
    for (int mi = 0; mi < 2; ++mi) {
      const int r = wm * 32 + mi * 16 + l15;
      a[mi] = *(const bf16x8*)((const char*)hid + r * 512 + ((((s * 4 + lq)) ^ (r & 7)) << 4));
    }
#pragma unroll
    for (int ni = 0; ni < 4; ++ni)
      b[ni] = *(const bf16x8*)(wb + lq * 4096 + (cbase + ni * 16 + l15) * 16);
#pragma unroll
    for (int ni = 0; ni < 4; ++ni)
#pragma unroll
      for (int mi = 0; mi < 2; ++mi)
        acc[mi][ni] = __builtin_amdgcn_mfma_f32_16x16x32_bf16(b[ni], a[mi], acc[mi][ni], 0, 0, 0);
    __syncthreads();
  }

  // ---------------- LN: per-row over regs + 2 shuffle stages ---------------
  f32x4 b2q[4];
#pragma unroll
  for (int ni = 0; ni < 4; ++ni)
    b2q[ni] = *(const f32x4*)(B2 + cbase + ni * 16 + lq * 4);
  float mean_[2], inv_[2];
#pragma unroll
  for (int mi = 0; mi < 2; ++mi) {
    float s1 = 0.f, s2 = 0.f;
#pragma unroll
    for (int ni = 0; ni < 4; ++ni)
#pragma unroll
      for (int i = 0; i < 4; ++i) {
        const float v = acc[mi][ni][i] + b2q[ni][i];
        s1 += v; s2 += v * v;
      }
    s1 += __shfl_xor(s1, 16); s2 += __shfl_xor(s2, 16);
    s1 += __shfl_xor(s1, 32); s2 += __shfl_xor(s2, 32);
    mean_[mi] = s1; inv_[mi] = s2;  // per-wave 64-col partials for row r
  }
  if (lq == 0) {
#pragma unroll
    for (int mi = 0; mi < 2; ++mi) {
      const int r = wm * 32 + mi * 16 + l15;
      redbuf[(r * 4 + wn) * 2 + 0] = mean_[mi];
      redbuf[(r * 4 + wn) * 2 + 1] = inv_[mi];
    }
  }
  __syncthreads();  // redbuf ready
#pragma unroll
  for (int mi = 0; mi < 2; ++mi) {
    const int r = wm * 32 + mi * 16 + l15;
    float t1 = 0.f, t2 = 0.f;
#pragma unroll
    for (int w = 0; w < 4; ++w) {
      t1 += redbuf[(r * 4 + w) * 2 + 0];
      t2 += redbuf[(r * 4 + w) * 2 + 1];
    }
    const float mean = t1 * (1.f / 256.f);
    const float var = t2 * (1.f / 256.f) - mean * mean;
    mean_[mi] = mean;
    inv_[mi] = rsqrtf(var + LN_EPS);
  }
  // (hidden reads finished at GEMM2's final barrier; safe to overwrite Abuf)

  f32x4 gq[4], bq[4];
#pragma unroll
  for (int ni = 0; ni < 4; ++ni) {
    gq[ni] = *(const f32x4*)(LG + cbase + ni * 16 + lq * 4);
    bq[ni] = *(const f32x4*)(LB + cbase + ni * 16 + lq * 4);
  }

  if (NODE) {
    float* ob = (float*)Abuf;  // 64 x 128 f32 per half-pass (32KB)
#pragma unroll
    for (int h = 0; h < 2; ++h) {
      if ((cbase >> 7) == h) {
#pragma unroll
        for (int mi = 0; mi < 2; ++mi) {
          const int r = wm * 32 + mi * 16 + l15;
#pragma unroll
          for (int ni = 0; ni < 4; ++ni) {
            const int cl4 = cbase - h * 128 + ni * 16 + lq * 4;
            f32x4 y;
#pragma unroll
            for (int i = 0; i < 4; ++i)
              y[i] = (acc[mi][ni][i] + b2q[ni][i] - mean_[mi]) * inv_[mi] * gq[ni][i] + bq[ni][i];
            *(f32x4*)((char*)ob + r * 512 + ((((cl4 >> 2) ^ (r & 7))) << 4)) = y;
          }
        }
      }
      __syncthreads();  // ob(h) ready
#pragma unroll
      for (int j = 0; j < 4; ++j) {
        const int gg = tid + 512 * j;
        const int row = gg >> 5, Lc = gg & 31;
        const int grow = r0 + row;
        if (grow < M) {
          f32x4 v = *(const f32x4*)(ob + row * 128 + ((Lc ^ (row & 7)) << 2));
          const f32x4 xr = *(const f32x4*)(Resid + (size_t)grow * DD + h * 128 + Lc * 4);
          v = v + xr;
          *(f32x4*)(OutF + (size_t)grow * DD + h * 128 + Lc * 4) = v;
          s16x4 o; o.x = f2bf(v.x); o.y = f2bf(v.y); o.z = f2bf(v.z); o.w = f2bf(v.w);
          *(s16x4*)(XbOut + (size_t)grow * DD + h * 128 + Lc * 4) = o;
        }
      }
      if (h == 0) __syncthreads();  // pass-0 reads done before pass-1 writes
    }
  } else {
    short* ob = (short*)Abuf;  // 64 x 256 bf16, 16B-granule swizzle
#pragma unroll
    for (int mi = 0; mi < 2; ++mi) {
      const int r = wm * 32 + mi * 16 + l15;
#pragma unroll
      for (int ni = 0; ni < 4; ++ni) {
        const int c4 = cbase + ni * 16 + lq * 4;
        s16x4 o;
#pragma unroll
        for (int i = 0; i < 4; ++i)
          o[i] = f2bf((acc[mi][ni][i] + b2q[ni][i] - mean_[mi]) * inv_[mi] * gq[ni][i] + bq[ni][i]);
        *(s16x4*)((char*)ob + r * 512 + (((c4 >> 3) ^ (r & 7)) << 4) + (c4 & 7) * 2) = o;
      }
    }
    __syncthreads();  // ob ready
#pragma unroll
    for (int j = 0; j < 4; ++j) {
      const int gg = tid + 512 * j;
      const int row = gg >> 5, Lg = gg & 31;
      const int grow = r0 + row;
      if (grow < M) {
        const i32x4 v = *(const i32x4*)(ob + row * DD + ((Lg ^ (row & 7)) << 3));
        *(i32x4*)(OutB + (size_t)grow * DD + Lg * 8) = v;
      }
    }
  }
}

// ----------------------- aggregation: wave per node, CSR-sorted efeat ------
__global__ __launch_bounds__(256) void aggregate_kernel(
    const short* __restrict__ xb, const short* __restrict__ efs,
    const int* __restrict__ offs, const int* __restrict__ ssrc,
    short* __restrict__ aggr) {
  const int w = (blockIdx.x * blockDim.x + threadIdx.x) >> 6;
  if (w >= NNODE) return;
  const int lane = threadIdx.x & 63;
  const int beg = offs[w], end = offs[w + 1];
  float s0 = 0.f, s1 = 0.f, s2 = 0.f, s3 = 0.f;
  int p = beg;
  for (; p + 3 < end; p += 4) {
    const int a0 = ssrc[p], a1 = ssrc[p + 1], a2 = ssrc[p + 2], a3 = ssrc[p + 3];
    const s16x4 e0 = *(const s16x4*)(efs + (size_t)p * DD + lane * 4);
    const s16x4 e1 = *(const s16x4*)(efs + (size_t)(p + 1) * DD + lane * 4);
    const s16x4 e2 = *(const s16x4*)(efs + (size_t)(p + 2) * DD + lane * 4);
    const s16x4 e3 = *(const s16x4*)(efs + (size_t)(p + 3) * DD + lane * 4);
    const s16x4 x0 = *(const s16x4*)(xb + (size_t)a0 * DD + lane * 4);
    const s16x4 x1 = *(const s16x4*)(xb + (size_t)a1 * DD + lane * 4);
    const s16x4 x2 = *(const s16x4*)(xb + (size_t)a2 * DD + lane * 4);
    const s16x4 x3 = *(const s16x4*)(xb + (size_t)a3 * DD + lane * 4);
    s0 += bf2f(e0.x) + bf2f(x0.x) + bf2f(e1.x) + bf2f(x1.x) +
          bf2f(e2.x) + bf2f(x2.x) + bf2f(e3.x) + bf2f(x3.x);
    s1 += bf2f(e0.y) + bf2f(x0.y) + bf2f(e1.y) + bf2f(x1.y) +
          bf2f(e2.y) + bf2f(x2.y) + bf2f(e3.y) + bf2f(x3.y);
    s2 += bf2f(e0.z) + bf2f(x0.z) + bf2f(e1.z) + bf2f(x1.z) +
          bf2f(e2.z) + bf2f(x2.z) + bf2f(e3.z) + bf2f(x3.z);
    s3 += bf2f(e0.w) + bf2f(x0.w) + bf2f(e1.w) + bf2f(x1.w) +
          bf2f(e2.w) + bf2f(x2.w) + bf2f(e3.w) + bf2f(x3.w);
  }
  for (; p < end; ++p) {
    const s16x4 ev = *(const s16x4*)(efs + (size_t)p * DD + lane * 4);
    const s16x4 xv = *(const s16x4*)(xb + (size_t)ssrc[p] * DD + lane * 4);
    s0 += bf2f(ev.x) + bf2f(xv.x);
    s1 += bf2f(ev.y) + bf2f(xv.y);
    s2 += bf2f(ev.z) + bf2f(xv.z);
    s3 += bf2f(ev.w) + bf2f(xv.w);
  }
  s16x4 o; o.x = f2bf(s0); o.y = f2bf(s1); o.z = f2bf(s2); o.w = f2bf(s3);
  *(s16x4*)(aggr + (size_t)w * DD + lane * 4) = o;
}

__global__ void count_kernel(const int* __restrict__ tgt, int* __restrict__ deg) {
  const int e = blockIdx.x * 256 + threadIdx.x;
  if (e < NEDGE) atomicAdd(&deg[tgt[e]], 1);
}

// ---------- 3-stage multi-block exclusive scan ----------
__global__ __launch_bounds__(256) void scan1_kernel(
    const int* __restrict__ deg, int* __restrict__ locex, int* __restrict__ bsum) {
  __shared__ int sh[256];
  const int t = threadIdx.x, b = blockIdx.x;
  const int idx = b * 256 + t;
  const int v = (idx < NNODE) ? deg[idx] : 0;
  sh[t] = v;
  __syncthreads();
#pragma unroll
  for (int off = 1; off < 256; off <<= 1) {
    const int add = (t >= off) ? sh[t - off] : 0;
    __syncthreads();
    sh[t] += add;
    __syncthreads();
  }
  if (idx < NNODE) locex[idx] = sh[t] - v;
  if (t == 255) bsum[b] = sh[255];
}

__global__ __launch_bounds__(512) void scan2_kernel(int* __restrict__ bsum, int nb) {
  __shared__ int sh[512];
  const int t = threadIdx.x;
  const int v = (t < nb) ? bsum[t] : 0;
  sh[t] = v;
  __syncthreads();
#pragma unroll
  for (int off = 1; off < 512; off <<= 1) {
    const int add = (t >= off) ? sh[t - off] : 0;
    __syncthreads();
    sh[t] += add;
    __syncthreads();
  }
  if (t < nb) bsum[t] = sh[t] - v;
}

__global__ __launch_bounds__(256) void scan3_kernel(
    const int* __restrict__ locex, const int* __restrict__ bsum,
    int* __restrict__ offs, int* __restrict__ cur) {
  const int idx = blockIdx.x * 256 + threadIdx.x;
  if (idx < NNODE) {
    const int o = locex[idx] + bsum[blockIdx.x];
    offs[idx] = o;
    cur[idx] = o;
  }
  if (idx == 0) offs[NNODE] = NEDGE;
}

__global__ void fill_kernel(const int* __restrict__ src, const int* __restrict__ tgt,
                            int* cur, int* seid, int* ssrc) {
  const int e = blockIdx.x * 256 + threadIdx.x;
  if (e < NEDGE) {
    const int t = tgt[e];
    const int p = atomicAdd(&cur[t], 1);
    seid[p] = e;
    ssrc[p] = src[e];
  }
}

__global__ void cvt4_kernel(const float* __restrict__ src, short* __restrict__ dst, int n4) {
  for (int i = blockIdx.x * blockDim.x + threadIdx.x; i < n4; i += gridDim.x * blockDim.x) {
    const f32x4 v = ((const f32x4*)src)[i];
    s16x4 o;
    o.x = f2bf(v.x); o.y = f2bf(v.y); o.z = f2bf(v.z); o.w = f2bf(v.w);
    ((s16x4*)dst)[i] = o;
  }
}

__global__ __launch_bounds__(256) void gather_cvt_kernel(
    const float* __restrict__ src, const int* __restrict__ perm,
    short* __restrict__ dst, int n) {
  const int w = (blockIdx.x * blockDim.x + threadIdx.x) >> 6;
  if (w >= n) return;
  const int lane = threadIdx.x & 63;
  const f32x4 v = *(const f32x4*)(src + (size_t)perm[w] * DD + lane * 4);
  s16x4 o; o.x = f2bf(v.x); o.y = f2bf(v.y); o.z = f2bf(v.z); o.w = f2bf(v.w);
  *(s16x4*)(dst + (size_t)w * DD + lane * 4) = o;
}

// ---------------------------------------------------------------------------
extern "C" void kernel_launch(void* const* d_in, const int* in_sizes, int n_in,
                              void* d_out, int out_size, void* d_ws, size_t ws_size,
                              hipStream_t stream) {
  const float* x_in = (const float*)d_in[0];
  const float* ea_f = (const float*)d_in[1];
  const float* e1w = (const float*)d_in[2];
  const float* e1b = (const float*)d_in[3];
  const float* e2w = (const float*)d_in[4];
  const float* e2b = (const float*)d_in[5];
  const float* elg = (const float*)d_in[6];
  const float* elb = (const float*)d_in[7];
  const float* n1w = (const float*)d_in[8];
  const float* n1b = (const float*)d_in[9];
  const float* n2w = (const float*)d_in[10];
  const float* n2b = (const float*)d_in[11];
  const float* nlg = (const float*)d_in[12];
  const float* nlb = (const float*)d_in[13];
  const int* eidx = (const int*)d_in[14];
  float* x = (float*)d_out;

  char* p = (char*)d_ws;
  auto take = [&](size_t bytes) {
    char* r = p;
    p += (bytes + 255) & ~(size_t)255;
    return r;
  };
  short* efeat = (short*)take((size_t)NEDGE * DD * 2);
  short* aggr = (short*)take((size_t)NNODE * DD * 2);
  short* xb = (short*)take((size_t)NNODE * DD * 2);
  short* we1t = (short*)take((size_t)NLAY * DD * DD * 2);
  short* we2t = (short*)take((size_t)NLAY * DD * DD * 2);
  short* wn1t = (short*)take((size_t)NLAY * DD * DD * 2);
  short* wn2t = (short*)take((size_t)NLAY * DD * DD * 2);
  int* deg = (int*)take((size_t)NNODE * 4);
  int* offs = (int*)take((size_t)(NNODE + 1) * 4);
  int* cur = (int*)take((size_t)NNODE * 4);
  int* seid = (int*)take((size_t)NEDGE * 4);
  int* ssrc = (int*)take((size_t)NEDGE * 4);
  int* locex = (int*)take((size_t)(NNODE + 256) * 4);
  int* bsum = (int*)take(512 * 4);
  short* eab = (short*)take((size_t)NEDGE * DD * 2);
  const bool use_eab = ((size_t)(p - (char*)d_ws) <= ws_size);

  const int SMEM = 67584;
  hipFuncSetAttribute((const void*)mlp_kernel<true, false>,
                      hipFuncAttributeMaxDynamicSharedMemorySize, SMEM);
  hipFuncSetAttribute((const void*)mlp_kernel<false, false>,
                      hipFuncAttributeMaxDynamicSharedMemorySize, SMEM);
  hipFuncSetAttribute((const void*)mlp_kernel<true, true>,
                      hipFuncAttributeMaxDynamicSharedMemorySize, SMEM);

  hipMemcpyAsync(x, x_in, (size_t)NNODE * DD * 4, hipMemcpyDeviceToDevice, stream);

  cvtw_kernel<<<288, 256, 0, stream>>>(e1w, we1t, NLAY);
  cvtw_kernel<<<288, 256, 0, stream>>>(e2w, we2t, NLAY);
  cvtw_kernel<<<288, 256, 0, stream>>>(n1w, wn1t, NLAY);
  cvtw_kernel<<<288, 256, 0, stream>>>(n2w, wn2t, NLAY);
  cvt4_kernel<<<2048, 256, 0, stream>>>(x_in, xb, NNODE * DD / 4);

  const int NB = (NNODE + 255) / 256;  // 391
  hipMemsetAsync(deg, 0, (size_t)NNODE * 4, stream);
  count_kernel<<<(NEDGE + 255) / 256, 256, 0, stream>>>(eidx + NEDGE, deg);
  scan1_kernel<<<NB, 256, 0, stream>>>(deg, locex, bsum);
  scan2_kernel<<<1, 512, 0, stream>>>(bsum, NB);
  scan3_kernel<<<NB, 256, 0, stream>>>(locex, bsum, offs, cur);
  fill_kernel<<<(NEDGE + 255) / 256, 256, 0, stream>>>(eidx, eidx + NEDGE, cur, seid, ssrc);
  if (use_eab)
    gather_cvt_kernel<<<NEDGE / 4, 256, 0, stream>>>(ea_f, seid, eab, NEDGE);

  const int egrid = (NEDGE + 63) / 64;
  const int ngrid = (NNODE + 63) / 64;
  for (int l = 0; l < NLAY; ++l) {
    if (use_eab) {
      mlp_kernel<true, false><<<egrid, 512, SMEM, stream>>>(
          eab, nullptr, we1t + l * 65536, we2t + l * 65536, e1b + l * DD,
          e2b + l * DD, elg + l * DD, elb + l * DD, efeat, nullptr, nullptr,
          nullptr, NEDGE);
    } else {
      mlp_kernel<false, false><<<egrid, 512, SMEM, stream>>>(
          ea_f, seid, we1t + l * 65536, we2t + l * 65536, e1b + l * DD,
          e2b + l * DD, elg + l * DD, elb + l * DD, efeat, nullptr, nullptr,
          nullptr, NEDGE);
    }
    aggregate_kernel<<<(NNODE * 64 + 255) / 256, 256, 0, stream>>>(xb, efeat, offs, ssrc, aggr);
    mlp_kernel<true, true><<<ngrid, 512, SMEM, stream>>>(
        aggr, nullptr, wn1t + l * 65536, wn2t + l * 65536, n1b + l * DD,
        n2b + l * DD, nlg + l * DD, nlb + l * DD, nullptr, x, x, xb, NNODE);
  }
  (void)in_sizes; (void)n_in; (void)out_size; (void)ws_size;
}

// Round 12
// 2631.927 us; speedup vs baseline: 2.2033x; 1.1294x over previous
//
#include <hip/hip_runtime.h>
#include <stdint.h>

#define DD 256
#define NEDGE 300000
#define NNODE 100000
#define NLAY 9
#define LN_EPS 1e-5f

typedef __attribute__((ext_vector_type(8))) short bf16x8;
typedef __attribute__((ext_vector_type(4))) short s16x4;
typedef __attribute__((ext_vector_type(4))) float f32x4;
typedef __attribute__((ext_vector_type(4))) int i32x4;

static __device__ __forceinline__ short f2bf(float f) {
  union { float f; uint32_t u; } v; v.f = f;
  uint32_t r = (v.u + 0x7FFFu + ((v.u >> 16) & 1u)) >> 16;
  return (short)(uint16_t)r;
}
static __device__ __forceinline__ float bf2f(short s) {
  union { uint32_t u; float f; } v; v.u = ((uint32_t)(uint16_t)s) << 16;
  return v.f;
}
// packed bf16 pair add: r = bf16(a.lo+b.lo) | bf16(a.hi+b.hi)<<16
static __device__ __forceinline__ int addbf2(int a, int b) {
  const float a0 = bf2f((short)(a & 0xffff)), a1 = bf2f((short)(((uint32_t)a) >> 16));
  const float b0 = bf2f((short)(b & 0xffff)), b1 = bf2f((short)(((uint32_t)b) >> 16));
  const uint16_t r0 = (uint16_t)f2bf(a0 + b0), r1 = (uint16_t)f2bf(a1 + b1);
  return (int)(((uint32_t)r1 << 16) | r0);
}

static __device__ __forceinline__ void gld16(const void* g, void* l) {
  __builtin_amdgcn_global_load_lds((const __attribute__((address_space(1))) void*)g,
                                   (__attribute__((address_space(3))) void*)l, 16, 0, 0);
}

// ---------------------------------------------------------------------------
// Weight pre-transpose + bf16: global chunk j (16B) = kq*256+col holds
// W[col][kq*8..kq*8+7]; K-slice s (32 k) = chunks [s*1024, (s+1)*1024).
// ---------------------------------------------------------------------------
__global__ void cvtw_kernel(const float* __restrict__ src, short* __restrict__ dst, int nmat) {
  const int total = nmat * 8192;
  for (int j = blockIdx.x * blockDim.x + threadIdx.x; j < total; j += gridDim.x * blockDim.x) {
    const int m = j >> 13;
    const int jj = j & 8191;
    const int col = jj & 255;
    const int kq = jj >> 8;
    const float* s = src + (size_t)m * 65536 + col * 256 + kq * 8;
    const f32x4 u0 = *(const f32x4*)(s);
    const f32x4 u1 = *(const f32x4*)(s + 4);
    bf16x8 o;
#pragma unroll
    for (int q = 0; q < 4; ++q) { o[q] = f2bf(u0[q]); o[q + 4] = f2bf(u1[q]); }
    *(bf16x8*)(dst + (size_t)j * 8) = o;
  }
}

// ---------------------------------------------------------------------------
// Fused MLP v12 — v11 + bf16 residual chain.
// 512 thr = 8 waves (2M x 4N); tile 64r x 256c; wave 32r x 64c; acc[2][4].
// Swapped-operand MFMA (lane=row, regs=4 cols). Residual read from XbOut
// (bf16, in-place); f32 OutF written ONLY when non-null (last layer).
// LDS: Wslot0 @0, Wslot1 @16384, A/hidden @32768 (32KB), red @65536 (2KB).
// ---------------------------------------------------------------------------
template<bool A_BF16, bool NODE>
__global__ __launch_bounds__(512, 4) void mlp_kernel(
    const void* __restrict__ Ain, const int* __restrict__ rowmap,
    const short* __restrict__ W1t, const short* __restrict__ W2t,
    const float* __restrict__ B1, const float* __restrict__ B2,
    const float* __restrict__ LG, const float* __restrict__ LB,
    short* __restrict__ OutB, float* __restrict__ OutF,
    short* __restrict__ XbOut, int M) {
  extern __shared__ char smem[];
  char* Abuf = smem + 32768;
  float* redbuf = (float*)(smem + 65536);
  const int tid = threadIdx.x;
  const int lane = tid & 63;
  const int wv = tid >> 6;
  const int wm = wv >> 2, wn = wv & 3;
  const int l15 = lane & 15, lq = lane >> 4;
  const int cbase = wn * 64;
  const int r0 = blockIdx.x * 64;

  auto stageW = [&](const short* Wt, int s, int slot) {
#pragma unroll
    for (int j = 0; j < 2; ++j) {
      const int c = tid + 512 * j;
      gld16(Wt + ((size_t)s * 1024 + c) * 8, smem + slot * 16384 + c * 16);
    }
  };

  // ---- stage whole A tile: [kq][row][16B], conflict-free ----
  if (A_BF16) {
    const short* A = (const short*)Ain;
#pragma unroll
    for (int j = 0; j < 4; ++j) {
      const int c = tid + 512 * j;
      const int row = c & 63, kq = c >> 6;
      const int gr = min(r0 + row, M - 1);
      gld16(A + (size_t)gr * DD + kq * 8, Abuf + c * 16);
    }
  } else {
    const float* A = (const float*)Ain;
#pragma unroll
    for (int j = 0; j < 4; ++j) {
      const int c = tid + 512 * j;
      const int row = c & 63, kq = c >> 6;
      const int gr0 = min(r0 + row, M - 1);
      const int gr = rowmap ? rowmap[gr0] : gr0;
      const f32x4 u0 = *(const f32x4*)(A + (size_t)gr * DD + kq * 8);
      const f32x4 u1 = *(const f32x4*)(A + (size_t)gr * DD + kq * 8 + 4);
      bf16x8 o;
#pragma unroll
      for (int q = 0; q < 4; ++q) { o[q] = f2bf(u0[q]); o[q + 4] = f2bf(u1[q]); }
      *(bf16x8*)(Abuf + c * 16) = o;
    }
  }
  stageW(W1t, 0, 0);
  __syncthreads();  // A + W1 slice0 ready

  f32x4 acc[2][4];
#pragma unroll
  for (int mi = 0; mi < 2; ++mi)
#pragma unroll
    for (int ni = 0; ni < 4; ++ni) acc[mi][ni] = (f32x4){0.f, 0.f, 0.f, 0.f};

  // ---------------- GEMM1: h^T = (A @ W1^T)^T via mfma(W, A, acc) ----------
#pragma unroll
  for (int s = 0; s < 8; ++s) {
    if (s < 7) stageW(W1t, s + 1, (s + 1) & 1);
    else       stageW(W2t, 0, 0);
    const char* wb = smem + (s & 1) * 16384;
    bf16x8 a[2], b[4];
#pragma unroll
    for (int mi = 0; mi < 2; ++mi)
      a[mi] = *(const bf16x8*)(Abuf + (((s * 4 + lq) * 64) + wm * 32 + mi * 16 + l15) * 16);
#pragma unroll
    for (int ni = 0; ni < 4; ++ni)
      b[ni] = *(const bf16x8*)(wb + lq * 4096 + (cbase + ni * 16 + l15) * 16);
#pragma unroll
    for (int ni = 0; ni < 4; ++ni)
#pragma unroll
      for (int mi = 0; mi < 2; ++mi)
        acc[mi][ni] = __builtin_amdgcn_mfma_f32_16x16x32_bf16(b[ni], a[mi], acc[mi][ni], 0, 0, 0);
    __syncthreads();
  }

  // ---- EPI1: bias+relu -> hidden; thread holds 4 consecutive cols --------
  short* hid = (short*)Abuf;
  {
    f32x4 b1q[4];
#pragma unroll
    for (int ni = 0; ni < 4; ++ni)
      b1q[ni] = *(const f32x4*)(B1 + cbase + ni * 16 + lq * 4);
#pragma unroll
    for (int mi = 0; mi < 2; ++mi) {
      const int r = wm * 32 + mi * 16 + l15;
#pragma unroll
      for (int ni = 0; ni < 4; ++ni) {
        const int c4 = cbase + ni * 16 + lq * 4;
        s16x4 o;
#pragma unroll
        for (int i = 0; i < 4; ++i) {
          o[i] = f2bf(fmaxf(acc[mi][ni][i] + b1q[ni][i], 0.f));
          acc[mi][ni][i] = 0.f;
        }
        *(s16x4*)((char*)hid + r * 512 + (((c4 >> 3) ^ (r & 7)) << 4) + (c4 & 7) * 2) = o;
      }
    }
  }
  __syncthreads();  // hidden ready

  // ---------------- GEMM2: y^T = (h @ W2^T)^T ------------------------------
#pragma unroll
  for (int s = 0; s < 8; ++s) {
    if (s < 7) stageW(W2t, s + 1, (s + 1) & 1);
    const char* wb = smem + (s & 1) * 16384;
    bf16x8 a[2], b[4];
#pragma unroll
    for (int mi = 0; mi < 2; ++mi) {
      const int r = wm * 32 + mi * 16 + l15;
      a[mi] = *(const bf16x8*)((const char*)hid + r * 512 + ((((s * 4 + lq)) ^ (r & 7)) << 4));
    }
#pragma unroll
    for (int ni = 0; ni < 4; ++ni)
      b[ni] = *(const bf16x8*)(wb + lq * 4096 + (cbase + ni * 16 + l15) * 16);
#pragma unroll
    for (int ni = 0; ni < 4; ++ni)
#pragma unroll
      for (int mi = 0; mi < 2; ++mi)
        acc[mi][ni] = __builtin_amdgcn_mfma_f32_16x16x32_bf16(b[ni], a[mi], acc[mi][ni], 0, 0, 0);
    __syncthreads();
  }

  // ---------------- LN: per-row over regs + 2 shuffle stages ---------------
  f32x4 b2q[4];
#pragma unroll
  for (int ni = 0; ni < 4; ++ni)
    b2q[ni] = *(const f32x4*)(B2 + cbase + ni * 16 + lq * 4);
  float mean_[2], inv_[2];
#pragma unroll
  for (int mi = 0; mi < 2; ++mi) {
    float s1 = 0.f, s2 = 0.f;
#pragma unroll
    for (int ni = 0; ni < 4; ++ni)
#pragma unroll
      for (int i = 0; i < 4; ++i) {
        const float v = acc[mi][ni][i] + b2q[ni][i];
        s1 += v; s2 += v * v;
      }
    s1 += __shfl_xor(s1, 16); s2 += __shfl_xor(s2, 16);
    s1 += __shfl_xor(s1, 32); s2 += __shfl_xor(s2, 32);
    mean_[mi] = s1; inv_[mi] = s2;  // per-wave 64-col partials for row r
  }
  if (lq == 0) {
#pragma unroll
    for (int mi = 0; mi < 2; ++mi) {
      const int r = wm * 32 + mi * 16 + l15;
      redbuf[(r * 4 + wn) * 2 + 0] = mean_[mi];
      redbuf[(r * 4 + wn) * 2 + 1] = inv_[mi];
    }
  }
  __syncthreads();  // redbuf ready
#pragma unroll
  for (int mi = 0; mi < 2; ++mi) {
    const int r = wm * 32 + mi * 16 + l15;
    float t1 = 0.f, t2 = 0.f;
#pragma unroll
    for (int w = 0; w < 4; ++w) {
      t1 += redbuf[(r * 4 + w) * 2 + 0];
      t2 += redbuf[(r * 4 + w) * 2 + 1];
    }
    const float mean = t1 * (1.f / 256.f);
    const float var = t2 * (1.f / 256.f) - mean * mean;
    mean_[mi] = mean;
    inv_[mi] = rsqrtf(var + LN_EPS);
  }

  f32x4 gq[4], bq[4];
#pragma unroll
  for (int ni = 0; ni < 4; ++ni) {
    gq[ni] = *(const f32x4*)(LG + cbase + ni * 16 + lq * 4);
    bq[ni] = *(const f32x4*)(LB + cbase + ni * 16 + lq * 4);
  }

  if (NODE) {
    const bool wantF = (OutF != nullptr);
    if (!wantF) {
      // layers 0..L-2: bf16-only output; resid add fused into copy-out
      short* ob = (short*)Abuf;
#pragma unroll
      for (int mi = 0; mi < 2; ++mi) {
        const int r = wm * 32 + mi * 16 + l15;
#pragma unroll
        for (int ni = 0; ni < 4; ++ni) {
          const int c4 = cbase + ni * 16 + lq * 4;
          s16x4 o;
#pragma unroll
          for (int i = 0; i < 4; ++i)
            o[i] = f2bf((acc[mi][ni][i] + b2q[ni][i] - mean_[mi]) * inv_[mi] * gq[ni][i] + bq[ni][i]);
          *(s16x4*)((char*)ob + r * 512 + (((c4 >> 3) ^ (r & 7)) << 4) + (c4 & 7) * 2) = o;
        }
      }
      __syncthreads();  // ob ready
#pragma unroll
      for (int j = 0; j < 4; ++j) {
        const int gg = tid + 512 * j;
        const int row = gg >> 5, Lg = gg & 31;
        const int grow = r0 + row;
        if (grow < M) {
          const i32x4 yv = *(const i32x4*)((const short*)ob + row * DD + ((Lg ^ (row & 7)) << 3));
          i32x4 xv = *(const i32x4*)(XbOut + (size_t)grow * DD + Lg * 8);
#pragma unroll
          for (int q = 0; q < 4; ++q) xv[q] = addbf2(yv[q], xv[q]);
          *(i32x4*)(XbOut + (size_t)grow * DD + Lg * 8) = xv;
        }
      }
    } else {
      // last layer: f32 two-pass output (full precision add) + bf16 mirror
      float* ob = (float*)Abuf;
#pragma unroll
      for (int h = 0; h < 2; ++h) {
        if ((cbase >> 7) == h) {
#pragma unroll
          for (int mi = 0; mi < 2; ++mi) {
            const int r = wm * 32 + mi * 16 + l15;
#pragma unroll
            for (int ni = 0; ni < 4; ++ni) {
              const int cl4 = cbase - h * 128 + ni * 16 + lq * 4;
              f32x4 y;
#pragma unroll
              for (int i = 0; i < 4; ++i)
                y[i] = (acc[mi][ni][i] + b2q[ni][i] - mean_[mi]) * inv_[mi] * gq[ni][i] + bq[ni][i];
              *(f32x4*)((char*)ob + r * 512 + ((((cl4 >> 2) ^ (r & 7))) << 4)) = y;
            }
          }
        }
        __syncthreads();  // ob(h) ready
#pragma unroll
        for (int j = 0; j < 4; ++j) {
          const int gg = tid + 512 * j;
          const int row = gg >> 5, Lc = gg & 31;
          const int grow = r0 + row;
          if (grow < M) {
            f32x4 v = *(const f32x4*)(ob + row * 128 + ((Lc ^ (row & 7)) << 2));
            const s16x4 xr = *(const s16x4*)(XbOut + (size_t)grow * DD + h * 128 + Lc * 4);
            v.x += bf2f(xr.x); v.y += bf2f(xr.y); v.z += bf2f(xr.z); v.w += bf2f(xr.w);
            *(f32x4*)(OutF + (size_t)grow * DD + h * 128 + Lc * 4) = v;
          }
        }
        if (h == 0) __syncthreads();  // pass-0 reads done before pass-1 writes
      }
    }
  } else {
    short* ob = (short*)Abuf;  // 64 x 256 bf16, 16B-granule swizzle
#pragma unroll
    for (int mi = 0; mi < 2; ++mi) {
      const int r = wm * 32 + mi * 16 + l15;
#pragma unroll
      for (int ni = 0; ni < 4; ++ni) {
        const int c4 = cbase + ni * 16 + lq * 4;
        s16x4 o;
#pragma unroll
        for (int i = 0; i < 4; ++i)
          o[i] = f2bf((acc[mi][ni][i] + b2q[ni][i] - mean_[mi]) * inv_[mi] * gq[ni][i] + bq[ni][i]);
        *(s16x4*)((char*)ob + r * 512 + (((c4 >> 3) ^ (r & 7)) << 4) + (c4 & 7) * 2) = o;
      }
    }
    __syncthreads();  // ob ready
#pragma unroll
    for (int j = 0; j < 4; ++j) {
      const int gg = tid + 512 * j;
      const int row = gg >> 5, Lg = gg & 31;
      const int grow = r0 + row;
      if (grow < M) {
        const i32x4 v = *(const i32x4*)((const short*)ob + row * DD + ((Lg ^ (row & 7)) << 3));
        *(i32x4*)(OutB + (size_t)grow * DD + Lg * 8) = v;
      }
    }
  }
}

// ----------------------- aggregation: wave per node, CSR-sorted efeat ------
__global__ __launch_bounds__(256) void aggregate_kernel(
    const short* __restrict__ xb, const short* __restrict__ efs,
    const int* __restrict__ offs, const int* __restrict__ ssrc,
    short* __restrict__ aggr) {
  const int w = (blockIdx.x * blockDim.x + threadIdx.x) >> 6;
  if (w >= NNODE) return;
  const int lane = threadIdx.x & 63;
  const int beg = offs[w], end = offs[w + 1];
  float s0 = 0.f, s1 = 0.f, s2 = 0.f, s3 = 0.f;
  int p = beg;
  for (; p + 3 < end; p += 4) {
    const int a0 = ssrc[p], a1 = ssrc[p + 1], a2 = ssrc[p + 2], a3 = ssrc[p + 3];
    const s16x4 e0 = *(const s16x4*)(efs + (size_t)p * DD + lane * 4);
    const s16x4 e1 = *(const s16x4*)(efs + (size_t)(p + 1) * DD + lane * 4);
    const s16x4 e2 = *(const s16x4*)(efs + (size_t)(p + 2) * DD + lane * 4);
    const s16x4 e3 = *(const s16x4*)(efs + (size_t)(p + 3) * DD + lane * 4);
    const s16x4 x0 = *(const s16x4*)(xb + (size_t)a0 * DD + lane * 4);
    const s16x4 x1 = *(const s16x4*)(xb + (size_t)a1 * DD + lane * 4);
    const s16x4 x2 = *(const s16x4*)(xb + (size_t)a2 * DD + lane * 4);
    const s16x4 x3 = *(const s16x4*)(xb + (size_t)a3 * DD + lane * 4);
    s0 += bf2f(e0.x) + bf2f(x0.x) + bf2f(e1.x) + bf2f(x1.x) +
          bf2f(e2.x) + bf2f(x2.x) + bf2f(e3.x) + bf2f(x3.x);
    s1 += bf2f(e0.y) + bf2f(x0.y) + bf2f(e1.y) + bf2f(x1.y) +
          bf2f(e2.y) + bf2f(x2.y) + bf2f(e3.y) + bf2f(x3.y);
    s2 += bf2f(e0.z) + bf2f(x0.z) + bf2f(e1.z) + bf2f(x1.z) +
          bf2f(e2.z) + bf2f(x2.z) + bf2f(e3.z) + bf2f(x3.z);
    s3 += bf2f(e0.w) + bf2f(x0.w) + bf2f(e1.w) + bf2f(x1.w) +
          bf2f(e2.w) + bf2f(x2.w) + bf2f(e3.w) + bf2f(x3.w);
  }
  for (; p < end; ++p) {
    const s16x4 ev = *(const s16x4*)(efs + (size_t)p * DD + lane * 4);
    const s16x4 xv = *(const s16x4*)(xb + (size_t)ssrc[p] * DD + lane * 4);
    s0 += bf2f(ev.x) + bf2f(xv.x);
    s1 += bf2f(ev.y) + bf2f(xv.y);
    s2 += bf2f(ev.z) + bf2f(xv.z);
    s3 += bf2f(ev.w) + bf2f(xv.w);
  }
  s16x4 o; o.x = f2bf(s0); o.y = f2bf(s1); o.z = f2bf(s2); o.w = f2bf(s3);
  *(s16x4*)(aggr + (size_t)w * DD + lane * 4) = o;
}

__global__ void count_kernel(const int* __restrict__ tgt, int* __restrict__ deg) {
  const int e = blockIdx.x * 256 + threadIdx.x;
  if (e < NEDGE) atomicAdd(&deg[tgt[e]], 1);
}

// ---------- 3-stage multi-block exclusive scan ----------
__global__ __launch_bounds__(256) void scan1_kernel(
    const int* __restrict__ deg, int* __restrict__ locex, int* __restrict__ bsum) {
  __shared__ int sh[256];
  const int t = threadIdx.x, b = blockIdx.x;
  const int idx = b * 256 + t;
  const int v = (idx < NNODE) ? deg[idx] : 0;
  sh[t] = v;
  __syncthreads();
#pragma unroll
  for (int off = 1; off < 256; off <<= 1) {
    const int add = (t >= off) ? sh[t - off] : 0;
    __syncthreads();
    sh[t] += add;
    __syncthreads();
  }
  if (idx < NNODE) locex[idx] = sh[t] - v;
  if (t == 255) bsum[b] = sh[255];
}

__global__ __launch_bounds__(512) void scan2_kernel(int* __restrict__ bsum, int nb) {
  __shared__ int sh[512];
  const int t = threadIdx.x;
  const int v = (t < nb) ? bsum[t] : 0;
  sh[t] = v;
  __syncthreads();
#pragma unroll
  for (int off = 1; off < 512; off <<= 1) {
    const int add = (t >= off) ? sh[t - off] : 0;
    __syncthreads();
    sh[t] += add;
    __syncthreads();
  }
  if (t < nb) bsum[t] = sh[t] - v;
}

__global__ __launch_bounds__(256) void scan3_kernel(
    const int* __restrict__ locex, const int* __restrict__ bsum,
    int* __restrict__ offs, int* __restrict__ cur) {
  const int idx = blockIdx.x * 256 + threadIdx.x;
  if (idx < NNODE) {
    const int o = locex[idx] + bsum[blockIdx.x];
    offs[idx] = o;
    cur[idx] = o;
  }
  if (idx == 0) offs[NNODE] = NEDGE;
}

__global__ void fill_kernel(const int* __restrict__ src, const int* __restrict__ tgt,
                            int* cur, int* seid, int* ssrc) {
  const int e = blockIdx.x * 256 + threadIdx.x;
  if (e < NEDGE) {
    const int t = tgt[e];
    const int p = atomicAdd(&cur[t], 1);
    seid[p] = e;
    ssrc[p] = src[e];
  }
}

__global__ void cvt4_kernel(const float* __restrict__ src, short* __restrict__ dst, int n4) {
  for (int i = blockIdx.x * blockDim.x + threadIdx.x; i < n4; i += gridDim.x * blockDim.x) {
    const f32x4 v = ((const f32x4*)src)[i];
    s16x4 o;
    o.x = f2bf(v.x); o.y = f2bf(v.y); o.z = f2bf(v.z); o.w = f2bf(v.w);
    ((s16x4*)dst)[i] = o;
  }
}

__global__ __launch_bounds__(256) void gather_cvt_kernel(
    const float* __restrict__ src, const int* __restrict__ perm,
    short* __restrict__ dst, int n) {
  const int w = (blockIdx.x * blockDim.x + threadIdx.x) >> 6;
  if (w >= n) return;
  const int lane = threadIdx.x & 63;
  const f32x4 v = *(const f32x4*)(src + (size_t)perm[w] * DD + lane * 4);
  s16x4 o; o.x = f2bf(v.x); o.y = f2bf(v.y); o.z = f2bf(v.z); o.w = f2bf(v.w);
  *(s16x4*)(dst + (size_t)w * DD + lane * 4) = o;
}

// ---------------------------------------------------------------------------
extern "C" void kernel_launch(void* const* d_in, const int* in_sizes, int n_in,
                              void* d_out, int out_size, void* d_ws, size_t ws_size,
                              hipStream_t stream) {
  const float* x_in = (const float*)d_in[0];
  const float* ea_f = (const float*)d_in[1];
  const float* e1w = (const float*)d_in[2];
  const float* e1b = (const float*)d_in[3];
  const float* e2w = (const float*)d_in[4];
  const float* e2b = (const float*)d_in[5];
  const float* elg = (const float*)d_in[6];
  const float* elb = (const float*)d_in[7];
  const float* n1w = (const float*)d_in[8];
  const float* n1b = (const float*)d_in[9];
  const float* n2w = (const float*)d_in[10];
  const float* n2b = (const float*)d_in[11];
  const float* nlg = (const float*)d_in[12];
  const float* nlb = (const float*)d_in[13];
  const int* eidx = (const int*)d_in[14];
  float* x = (float*)d_out;

  char* p = (char*)d_ws;
  auto take = [&](size_t bytes) {
    char* r = p;
    p += (bytes + 255) & ~(size_t)255;
    return r;
  };
  short* efeat = (short*)take((size_t)NEDGE * DD * 2);
  short* aggr = (short*)take((size_t)NNODE * DD * 2);
  short* xb = (short*)take((size_t)NNODE * DD * 2);
  short* we1t = (short*)take((size_t)NLAY * DD * DD * 2);
  short* we2t = (short*)take((size_t)NLAY * DD * DD * 2);
  short* wn1t = (short*)take((size_t)NLAY * DD * DD * 2);
  short* wn2t = (short*)take((size_t)NLAY * DD * DD * 2);
  int* deg = (int*)take((size_t)NNODE * 4);
  int* offs = (int*)take((size_t)(NNODE + 1) * 4);
  int* cur = (int*)take((size_t)NNODE * 4);
  int* seid = (int*)take((size_t)NEDGE * 4);
  int* ssrc = (int*)take((size_t)NEDGE * 4);
  int* locex = (int*)take((size_t)(NNODE + 256) * 4);
  int* bsum = (int*)take(512 * 4);
  short* eab = (short*)take((size_t)NEDGE * DD * 2);
  const bool use_eab = ((size_t)(p - (char*)d_ws) <= ws_size);

  const int SMEM = 67584;
  hipFuncSetAttribute((const void*)mlp_kernel<true, false>,
                      hipFuncAttributeMaxDynamicSharedMemorySize, SMEM);
  hipFuncSetAttribute((const void*)mlp_kernel<false, false>,
                      hipFuncAttributeMaxDynamicSharedMemorySize, SMEM);
  hipFuncSetAttribute((const void*)mlp_kernel<true, true>,
                      hipFuncAttributeMaxDynamicSharedMemorySize, SMEM);

  cvtw_kernel<<<288, 256, 0, stream>>>(e1w, we1t, NLAY);
  cvtw_kernel<<<288, 256, 0, stream>>>(e2w, we2t, NLAY);
  cvtw_kernel<<<288, 256, 0, stream>>>(n1w, wn1t, NLAY);
  cvtw_kernel<<<288, 256, 0, stream>>>(n2w, wn2t, NLAY);
  cvt4_kernel<<<2048, 256, 0, stream>>>(x_in, xb, NNODE * DD / 4);

  const int NB = (NNODE + 255) / 256;  // 391
  hipMemsetAsync(deg, 0, (size_t)NNODE * 4, stream);
  count_kernel<<<(NEDGE + 255) / 256, 256, 0, stream>>>(eidx + NEDGE, deg);
  scan1_kernel<<<NB, 256, 0, stream>>>(deg, locex, bsum);
  scan2_kernel<<<1, 512, 0, stream>>>(bsum, NB);
  scan3_kernel<<<NB, 256, 0, stream>>>(locex, bsum, offs, cur);
  fill_kernel<<<(NEDGE + 255) / 256, 256, 0, stream>>>(eidx, eidx + NEDGE, cur, seid, ssrc);
  if (use_eab)
    gather_cvt_kernel<<<NEDGE / 4, 256, 0, stream>>>(ea_f, seid, eab, NEDGE);

  const int egrid = (NEDGE + 63) / 64;
  const int ngrid = (NNODE + 63) / 64;
  for (int l = 0; l < NLAY; ++l) {
    if (use_eab) {
      mlp_kernel<true, false><<<egrid, 512, SMEM, stream>>>(
          eab, nullptr, we1t + l * 65536, we2t + l * 65536, e1b + l * DD,
          e2b + l * DD, elg + l * DD, elb + l * DD, efeat, nullptr,
          nullptr, NEDGE);
    } else {
      mlp_kernel<false, false><<<egrid, 512, SMEM, stream>>>(
          ea_f, seid, we1t + l * 65536, we2t + l * 65536, e1b + l * DD,
          e2b + l * DD, elg + l * DD, elb + l * DD, efeat, nullptr,
          nullptr, NEDGE);
    }
    aggregate_kernel<<<(NNODE * 64 + 255) / 256, 256, 0, stream>>>(xb, efeat, offs, ssrc, aggr);
    mlp_kernel<true, true><<<ngrid, 512, SMEM, stream>>>(
        aggr, nullptr, wn1t + l * 65536, wn2t + l * 65536, n1b + l * DD,
        n2b + l * DD, nlg + l * DD, nlb + l * DD, nullptr,
        (l == NLAY - 1) ? x : nullptr, xb, NNODE);
  }
  (void)in_sizes; (void)n_in; (void)out_size; (void)ws_size;
}

// Round 14
// 2578.755 us; speedup vs baseline: 2.2488x; 1.0206x over previous
//
#include <hip/hip_runtime.h>
#include <stdint.h>

#define DD 256
#define NEDGE 300000
#define NNODE 100000
#define NLAY 9
#define LN_EPS 1e-5f

typedef __attribute__((ext_vector_type(8))) short bf16x8;
typedef __attribute__((ext_vector_type(4))) short s16x4;
typedef __attribute__((ext_vector_type(4))) float f32x4;
typedef __attribute__((ext_vector_type(4))) int i32x4;

static __device__ __forceinline__ short f2bf(float f) {
  union { float f; uint32_t u; } v; v.f = f;
  uint32_t r = (v.u + 0x7FFFu + ((v.u >> 16) & 1u)) >> 16;
  return (short)(uint16_t)r;
}
static __device__ __forceinline__ float bf2f(short s) {
  union { uint32_t u; float f; } v; v.u = ((uint32_t)(uint16_t)s) << 16;
  return v.f;
}
// packed bf16 pair add: r = bf16(a.lo+b.lo) | bf16(a.hi+b.hi)<<16
static __device__ __forceinline__ int addbf2(int a, int b) {
  const float a0 = bf2f((short)(a & 0xffff)), a1 = bf2f((short)(((uint32_t)a) >> 16));
  const float b0 = bf2f((short)(b & 0xffff)), b1 = bf2f((short)(((uint32_t)b) >> 16));
  const uint16_t r0 = (uint16_t)f2bf(a0 + b0), r1 = (uint16_t)f2bf(a1 + b1);
  return (int)(((uint32_t)r1 << 16) | r0);
}

static __device__ __forceinline__ void gld16(const void* g, void* l) {
  __builtin_amdgcn_global_load_lds((const __attribute__((address_space(1))) void*)g,
                                   (__attribute__((address_space(3))) void*)l, 16, 0, 0);
}

// ---------------------------------------------------------------------------
// Weight pre-transpose + bf16: global chunk j (16B) = kq*256+col holds
// W[col][kq*8..kq*8+7]; K-slice s (32 k) = chunks [s*1024, (s+1)*1024).
// ---------------------------------------------------------------------------
__global__ void cvtw_kernel(const float* __restrict__ src, short* __restrict__ dst, int nmat) {
  const int total = nmat * 8192;
  for (int j = blockIdx.x * blockDim.x + threadIdx.x; j < total; j += gridDim.x * blockDim.x) {
    const int m = j >> 13;
    const int jj = j & 8191;
    const int col = jj & 255;
    const int kq = jj >> 8;
    const float* s = src + (size_t)m * 65536 + col * 256 + kq * 8;
    const f32x4 u0 = *(const f32x4*)(s);
    const f32x4 u1 = *(const f32x4*)(s + 4);
    bf16x8 o;
#pragma unroll
    for (int q = 0; q < 4; ++q) { o[q] = f2bf(u0[q]); o[q + 4] = f2bf(u1[q]); }
    *(bf16x8*)(dst + (size_t)j * 8) = o;
  }
}

// ---------------------------------------------------------------------------
// Fused MLP v14 — v13's fused aggregation, race-fixed via ping-pong x.
// NODE: reads XbIn (aggregation gather + residual), writes XbOut (never the
// same buffer) — no cross-block R/W race. Last layer writes f32 OutF only.
// 512 thr = 8 waves (2M x 4N); tile 64r x 256c; wave 32r x 64c; acc[2][4].
// LDS: Wslot0 @0, Wslot1 @16384, A/hidden @32768 (32KB), red @65536 (2KB).
// ---------------------------------------------------------------------------
template<bool A_BF16, bool NODE>
__global__ __launch_bounds__(512, 4) void mlp_kernel(
    const void* __restrict__ Ain, const int* __restrict__ rowmap,
    const int* __restrict__ offs, const int* __restrict__ ssrc,
    const short* __restrict__ XbIn,
    const short* __restrict__ W1t, const short* __restrict__ W2t,
    const float* __restrict__ B1, const float* __restrict__ B2,
    const float* __restrict__ LG, const float* __restrict__ LB,
    short* __restrict__ OutB, float* __restrict__ OutF,
    short* __restrict__ XbOut, int M) {
  extern __shared__ char smem[];
  char* Abuf = smem + 32768;
  float* redbuf = (float*)(smem + 65536);
  const int tid = threadIdx.x;
  const int lane = tid & 63;
  const int wv = tid >> 6;
  const int wm = wv >> 2, wn = wv & 3;
  const int l15 = lane & 15, lq = lane >> 4;
  const int cbase = wn * 64;
  const int r0 = blockIdx.x * 64;

  auto stageW = [&](const short* Wt, int s, int slot) {
#pragma unroll
    for (int j = 0; j < 2; ++j) {
      const int c = tid + 512 * j;
      gld16(Wt + ((size_t)s * 1024 + c) * 8, smem + slot * 16384 + c * 16);
    }
  };

  stageW(W1t, 0, 0);  // issue W DMA first so it overlaps the A stage below

  // ---- stage A tile: [kq][row][16B], conflict-free ----
  if (NODE) {
    // fused aggregation: lane r = node, wave j = kq slice (4 chunks)
    const short* efs = (const short*)Ain;
    const int r = tid & 63;
    const int j = tid >> 6;
    const int n = min(r0 + r, M - 1);
    const int beg = offs[n], end = offs[n + 1];
    float s[4][8];
#pragma unroll
    for (int c = 0; c < 4; ++c)
#pragma unroll
      for (int q = 0; q < 8; ++q) s[c][q] = 0.f;
    for (int p = beg; p < end; ++p) {
      const int src = ssrc[p];
#pragma unroll
      for (int c = 0; c < 4; ++c) {
        const int kq = j * 4 + c;
        const bf16x8 ev = *(const bf16x8*)(efs + (size_t)p * DD + kq * 8);
        const bf16x8 xv = *(const bf16x8*)(XbIn + (size_t)src * DD + kq * 8);
#pragma unroll
        for (int q = 0; q < 8; ++q) s[c][q] += bf2f(ev[q]) + bf2f(xv[q]);
      }
    }
#pragma unroll
    for (int c = 0; c < 4; ++c) {
      const int kq = j * 4 + c;
      bf16x8 o;
#pragma unroll
      for (int q = 0; q < 8; ++q) o[q] = f2bf(s[c][q]);
      *(bf16x8*)(Abuf + (kq * 64 + r) * 16) = o;
    }
  } else if (A_BF16) {
    const short* A = (const short*)Ain;
#pragma unroll
    for (int j = 0; j < 4; ++j) {
      const int c = tid + 512 * j;
      const int row = c & 63, kq = c >> 6;
      const int gr = min(r0 + row, M - 1);
      gld16(A + (size_t)gr * DD + kq * 8, Abuf + c * 16);
    }
  } else {
    const float* A = (const float*)Ain;
#pragma unroll
    for (int j = 0; j < 4; ++j) {
      const int c = tid + 512 * j;
      const int row = c & 63, kq = c >> 6;
      const int gr0 = min(r0 + row, M - 1);
      const int gr = rowmap ? rowmap[gr0] : gr0;
      const f32x4 u0 = *(const f32x4*)(A + (size_t)gr * DD + kq * 8);
      const f32x4 u1 = *(const f32x4*)(A + (size_t)gr * DD + kq * 8 + 4);
      bf16x8 o;
#pragma unroll
      for (int q = 0; q < 4; ++q) { o[q] = f2bf(u0[q]); o[q + 4] = f2bf(u1[q]); }
      *(bf16x8*)(Abuf + c * 16) = o;
    }
  }
  __syncthreads();  // A + W1 slice0 ready

  f32x4 acc[2][4];
#pragma unroll
  for (int mi = 0; mi < 2; ++mi)
#pragma unroll
    for (int ni = 0; ni < 4; ++ni) acc[mi][ni] = (f32x4){0.f, 0.f, 0.f, 0.f};

  // ---------------- GEMM1: h^T = (A @ W1^T)^T via mfma(W, A, acc) ----------
#pragma unroll
  for (int s = 0; s < 8; ++s) {
    if (s < 7) stageW(W1t, s + 1, (s + 1) & 1);
    else       stageW(W2t, 0, 0);
    const char* wb = smem + (s & 1) * 16384;
    bf16x8 a[2], b[4];
#pragma unroll
    for (int mi = 0; mi < 2; ++mi)
      a[mi] = *(const bf16x8*)(Abuf + (((s * 4 + lq) * 64) + wm * 32 + mi * 16 + l15) * 16);
#pragma unroll
    for (int ni = 0; ni < 4; ++ni)
      b[ni] = *(const bf16x8*)(wb + lq * 4096 + (cbase + ni * 16 + l15) * 16);
#pragma unroll
    for (int ni = 0; ni < 4; ++ni)
#pragma unroll
      for (int mi = 0; mi < 2; ++mi)
        acc[mi][ni] = __builtin_amdgcn_mfma_f32_16x16x32_bf16(b[ni], a[mi], acc[mi][ni], 0, 0, 0);
    __syncthreads();
  }

  // ---- EPI1: bias+relu -> hidden; thread holds 4 consecutive cols --------
  short* hid = (short*)Abuf;
  {
    f32x4 b1q[4];
#pragma unroll
    for (int ni = 0; ni < 4; ++ni)
      b1q[ni] = *(const f32x4*)(B1 + cbase + ni * 16 + lq * 4);
#pragma unroll
    for (int mi = 0; mi < 2; ++mi) {
      const int r = wm * 32 + mi * 16 + l15;
#pragma unroll
      for (int ni = 0; ni < 4; ++ni) {
        const int c4 = cbase + ni * 16 + lq * 4;
        s16x4 o;
#pragma unroll
        for (int i = 0; i < 4; ++i) {
          o[i] = f2bf(fmaxf(acc[mi][ni][i] + b1q[ni][i], 0.f));
          acc[mi][ni][i] = 0.f;
        }
        *(s16x4*)((char*)hid + r * 512 + (((c4 >> 3) ^ (r & 7)) << 4) + (c4 & 7) * 2) = o;
      }
    }
  }
  __syncthreads();  // hidden ready

  // ---------------- GEMM2: y^T = (h @ W2^T)^T ------------------------------
#pragma unroll
  for (int s = 0; s < 8; ++s) {
    if (s < 7) stageW(W2t, s + 1, (s + 1) & 1);
    const char* wb = smem + (s & 1) * 16384;
    bf16x8 a[2], b[4];
#pragma unroll
    for (int mi = 0; mi < 2; ++mi) {
      const int r = wm * 32 + mi * 16 + l15;
      a[mi] = *(const bf16x8*)((const char*)hid + r * 512 + ((((s * 4 + lq)) ^ (r & 7)) << 4));
    }
#pragma unroll
    for (int ni = 0; ni < 4; ++ni)
      b[ni] = *(const bf16x8*)(wb + lq * 4096 + (cbase + ni * 16 + l15) * 16);
#pragma unroll
    for (int ni = 0; ni < 4; ++ni)
#pragma unroll
      for (int mi = 0; mi < 2; ++mi)
        acc[mi][ni] = __builtin_amdgcn_mfma_f32_16x16x32_bf16(b[ni], a[mi], acc[mi][ni], 0, 0, 0);
    __syncthreads();
  }

  // ---------------- LN: per-row over regs + 2 shuffle stages ---------------
  f32x4 b2q[4];
#pragma unroll
  for (int ni = 0; ni < 4; ++ni)
    b2q[ni] = *(const f32x4*)(B2 + cbase + ni * 16 + lq * 4);
  float mean_[2], inv_[2];
#pragma unroll
  for (int mi = 0; mi < 2; ++mi) {
    float s1 = 0.f, s2 = 0.f;
#pragma unroll
    for (int ni = 0; ni < 4; ++ni)
#pragma unroll
      for (int i = 0; i < 4; ++i) {
        const float v = acc[mi][ni][i] + b2q[ni][i];
        s1 += v; s2 += v * v;
      }
    s1 += __shfl_xor(s1, 16); s2 += __shfl_xor(s2, 16);
    s1 += __shfl_xor(s1, 32); s2 += __shfl_xor(s2, 32);
    mean_[mi] = s1; inv_[mi] = s2;
  }
  if (lq == 0) {
#pragma unroll
    for (int mi = 0; mi < 2; ++mi) {
      const int r = wm * 32 + mi * 16 + l15;
      redbuf[(r * 4 + wn) * 2 + 0] = mean_[mi];
      redbuf[(r * 4 + wn) * 2 + 1] = inv_[mi];
    }
  }
  __syncthreads();  // redbuf ready
#pragma unroll
  for (int mi = 0; mi < 2; ++mi) {
    const int r = wm * 32 + mi * 16 + l15;
    float t1 = 0.f, t2 = 0.f;
#pragma unroll
    for (int w = 0; w < 4; ++w) {
      t1 += redbuf[(r * 4 + w) * 2 + 0];
      t2 += redbuf[(r * 4 + w) * 2 + 1];
    }
    const float mean = t1 * (1.f / 256.f);
    const float var = t2 * (1.f / 256.f) - mean * mean;
    mean_[mi] = mean;
    inv_[mi] = rsqrtf(var + LN_EPS);
  }

  f32x4 gq[4], bq[4];
#pragma unroll
  for (int ni = 0; ni < 4; ++ni) {
    gq[ni] = *(const f32x4*)(LG + cbase + ni * 16 + lq * 4);
    bq[ni] = *(const f32x4*)(LB + cbase + ni * 16 + lq * 4);
  }

  if (NODE) {
    const bool wantF = (OutF != nullptr);
    if (!wantF) {
      // layers 0..L-2: y + xbIn -> XbOut (bf16)
      short* ob = (short*)Abuf;
#pragma unroll
      for (int mi = 0; mi < 2; ++mi) {
        const int r = wm * 32 + mi * 16 + l15;
#pragma unroll
        for (int ni = 0; ni < 4; ++ni) {
          const int c4 = cbase + ni * 16 + lq * 4;
          s16x4 o;
#pragma unroll
          for (int i = 0; i < 4; ++i)
            o[i] = f2bf((acc[mi][ni][i] + b2q[ni][i] - mean_[mi]) * inv_[mi] * gq[ni][i] + bq[ni][i]);
          *(s16x4*)((char*)ob + r * 512 + (((c4 >> 3) ^ (r & 7)) << 4) + (c4 & 7) * 2) = o;
        }
      }
      __syncthreads();  // ob ready
#pragma unroll
      for (int j = 0; j < 4; ++j) {
        const int gg = tid + 512 * j;
        const int row = gg >> 5, Lg = gg & 31;
        const int grow = r0 + row;
        if (grow < M) {
          const i32x4 yv = *(const i32x4*)((const short*)ob + row * DD + ((Lg ^ (row & 7)) << 3));
          i32x4 xv = *(const i32x4*)(XbIn + (size_t)grow * DD + Lg * 8);
#pragma unroll
          for (int q = 0; q < 4; ++q) xv[q] = addbf2(yv[q], xv[q]);
          *(i32x4*)(XbOut + (size_t)grow * DD + Lg * 8) = xv;
        }
      }
    } else {
      // last layer: f32 two-pass output (full precision add vs bf16 xbIn)
      float* ob = (float*)Abuf;
#pragma unroll
      for (int h = 0; h < 2; ++h) {
        if ((cbase >> 7) == h) {
#pragma unroll
          for (int mi = 0; mi < 2; ++mi) {
            const int r = wm * 32 + mi * 16 + l15;
#pragma unroll
            for (int ni = 0; ni < 4; ++ni) {
              const int cl4 = cbase - h * 128 + ni * 16 + lq * 4;
              f32x4 y;
#pragma unroll
              for (int i = 0; i < 4; ++i)
                y[i] = (acc[mi][ni][i] + b2q[ni][i] - mean_[mi]) * inv_[mi] * gq[ni][i] + bq[ni][i];
              *(f32x4*)((char*)ob + r * 512 + ((((cl4 >> 2) ^ (r & 7))) << 4)) = y;
            }
          }
        }
        __syncthreads();  // ob(h) ready
#pragma unroll
        for (int j = 0; j < 4; ++j) {
          const int gg = tid + 512 * j;
          const int row = gg >> 5, Lc = gg & 31;
          const int grow = r0 + row;
          if (grow < M) {
            f32x4 v = *(const f32x4*)(ob + row * 128 + ((Lc ^ (row & 7)) << 2));
            const s16x4 xr = *(const s16x4*)(XbIn + (size_t)grow * DD + h * 128 + Lc * 4);
            v.x += bf2f(xr.x); v.y += bf2f(xr.y); v.z += bf2f(xr.z); v.w += bf2f(xr.w);
            *(f32x4*)(OutF + (size_t)grow * DD + h * 128 + Lc * 4) = v;
          }
        }
        if (h == 0) __syncthreads();
      }
    }
  } else {
    short* ob = (short*)Abuf;  // 64 x 256 bf16, 16B-granule swizzle
#pragma unroll
    for (int mi = 0; mi < 2; ++mi) {
      const int r = wm * 32 + mi * 16 + l15;
#pragma unroll
      for (int ni = 0; ni < 4; ++ni) {
        const int c4 = cbase + ni * 16 + lq * 4;
        s16x4 o;
#pragma unroll
        for (int i = 0; i < 4; ++i)
          o[i] = f2bf((acc[mi][ni][i] + b2q[ni][i] - mean_[mi]) * inv_[mi] * gq[ni][i] + bq[ni][i]);
        *(s16x4*)((char*)ob + r * 512 + (((c4 >> 3) ^ (r & 7)) << 4) + (c4 & 7) * 2) = o;
      }
    }
    __syncthreads();  // ob ready
#pragma unroll
    for (int j = 0; j < 4; ++j) {
      const int gg = tid + 512 * j;
      const int row = gg >> 5, Lg = gg & 31;
      const int grow = r0 + row;
      if (grow < M) {
        const i32x4 v = *(const i32x4*)((const short*)ob + row * DD + ((Lg ^ (row & 7)) << 3));
        *(i32x4*)(OutB + (size_t)grow * DD + Lg * 8) = v;
      }
    }
  }
}

__global__ void count_kernel(const int* __restrict__ tgt, int* __restrict__ deg) {
  const int e = blockIdx.x * 256 + threadIdx.x;
  if (e < NEDGE) atomicAdd(&deg[tgt[e]], 1);
}

// ---------- 3-stage multi-block exclusive scan ----------
__global__ __launch_bounds__(256) void scan1_kernel(
    const int* __restrict__ deg, int* __restrict__ locex, int* __restrict__ bsum) {
  __shared__ int sh[256];
  const int t = threadIdx.x, b = blockIdx.x;
  const int idx = b * 256 + t;
  const int v = (idx < NNODE) ? deg[idx] : 0;
  sh[t] = v;
  __syncthreads();
#pragma unroll
  for (int off = 1; off < 256; off <<= 1) {
    const int add = (t >= off) ? sh[t - off] : 0;
    __syncthreads();
    sh[t] += add;
    __syncthreads();
  }
  if (idx < NNODE) locex[idx] = sh[t] - v;
  if (t == 255) bsum[b] = sh[255];
}

__global__ __launch_bounds__(512) void scan2_kernel(int* __restrict__ bsum, int nb) {
  __shared__ int sh[512];
  const int t = threadIdx.x;
  const int v = (t < nb) ? bsum[t] : 0;
  sh[t] = v;
  __syncthreads();
#pragma unroll
  for (int off = 1; off < 512; off <<= 1) {
    const int add = (t >= off) ? sh[t - off] : 0;
    __syncthreads();
    sh[t] += add;
    __syncthreads();
  }
  if (t < nb) bsum[t] = sh[t] - v;
}

__global__ __launch_bounds__(256) void scan3_kernel(
    const int* __restrict__ locex, const int* __restrict__ bsum,
    int* __restrict__ offs, int* __restrict__ cur) {
  const int idx = blockIdx.x * 256 + threadIdx.x;
  if (idx < NNODE) {
    const int o = locex[idx] + bsum[blockIdx.x];
    offs[idx] = o;
    cur[idx] = o;
  }
  if (idx == 0) offs[NNODE] = NEDGE;
}

__global__ void fill_kernel(const int* __restrict__ src, const int* __restrict__ tgt,
                            int* cur, int* seid, int* ssrc) {
  const int e = blockIdx.x * 256 + threadIdx.x;
  if (e < NEDGE) {
    const int t = tgt[e];
    const int p = atomicAdd(&cur[t], 1);
    seid[p] = e;
    ssrc[p] = src[e];
  }
}

__global__ void cvt4_kernel(const float* __restrict__ src, short* __restrict__ dst, int n4) {
  for (int i = blockIdx.x * blockDim.x + threadIdx.x; i < n4; i += gridDim.x * blockDim.x) {
    const f32x4 v = ((const f32x4*)src)[i];
    s16x4 o;
    o.x = f2bf(v.x); o.y = f2bf(v.y); o.z = f2bf(v.z); o.w = f2bf(v.w);
    ((s16x4*)dst)[i] = o;
  }
}

__global__ __launch_bounds__(256) void gather_cvt_kernel(
    const float* __restrict__ src, const int* __restrict__ perm,
    short* __restrict__ dst, int n) {
  const int w = (blockIdx.x * blockDim.x + threadIdx.x) >> 6;
  if (w >= n) return;
  const int lane = threadIdx.x & 63;
  const f32x4 v = *(const f32x4*)(src + (size_t)perm[w] * DD + lane * 4);
  s16x4 o; o.x = f2bf(v.x); o.y = f2bf(v.y); o.z = f2bf(v.z); o.w = f2bf(v.w);
  *(s16x4*)(dst + (size_t)w * DD + lane * 4) = o;
}

// ---------------------------------------------------------------------------
extern "C" void kernel_launch(void* const* d_in, const int* in_sizes, int n_in,
                              void* d_out, int out_size, void* d_ws, size_t ws_size,
                              hipStream_t stream) {
  const float* x_in = (const float*)d_in[0];
  const float* ea_f = (const float*)d_in[1];
  const float* e1w = (const float*)d_in[2];
  const float* e1b = (const float*)d_in[3];
  const float* e2w = (const float*)d_in[4];
  const float* e2b = (const float*)d_in[5];
  const float* elg = (const float*)d_in[6];
  const float* elb = (const float*)d_in[7];
  const float* n1w = (const float*)d_in[8];
  const float* n1b = (const float*)d_in[9];
  const float* n2w = (const float*)d_in[10];
  const float* n2b = (const float*)d_in[11];
  const float* nlg = (const float*)d_in[12];
  const float* nlb = (const float*)d_in[13];
  const int* eidx = (const int*)d_in[14];
  float* x = (float*)d_out;

  char* p = (char*)d_ws;
  auto take = [&](size_t bytes) {
    char* r = p;
    p += (bytes + 255) & ~(size_t)255;
    return r;
  };
  short* efeat = (short*)take((size_t)NEDGE * DD * 2);
  short* xbA = (short*)take((size_t)NNODE * DD * 2);
  short* xbB = (short*)take((size_t)NNODE * DD * 2);
  short* we1t = (short*)take((size_t)NLAY * DD * DD * 2);
  short* we2t = (short*)take((size_t)NLAY * DD * DD * 2);
  short* wn1t = (short*)take((size_t)NLAY * DD * DD * 2);
  short* wn2t = (short*)take((size_t)NLAY * DD * DD * 2);
  int* deg = (int*)take((size_t)NNODE * 4);
  int* offs = (int*)take((size_t)(NNODE + 1) * 4);
  int* cur = (int*)take((size_t)NNODE * 4);
  int* seid = (int*)take((size_t)NEDGE * 4);
  int* ssrc = (int*)take((size_t)NEDGE * 4);
  int* locex = (int*)take((size_t)(NNODE + 256) * 4);
  int* bsum = (int*)take(512 * 4);
  short* eab = (short*)take((size_t)NEDGE * DD * 2);
  const bool use_eab = ((size_t)(p - (char*)d_ws) <= ws_size);

  const int SMEM = 67584;
  hipFuncSetAttribute((const void*)mlp_kernel<true, false>,
                      hipFuncAttributeMaxDynamicSharedMemorySize, SMEM);
  hipFuncSetAttribute((const void*)mlp_kernel<false, false>,
                      hipFuncAttributeMaxDynamicSharedMemorySize, SMEM);
  hipFuncSetAttribute((const void*)mlp_kernel<true, true>,
                      hipFuncAttributeMaxDynamicSharedMemorySize, SMEM);

  cvtw_kernel<<<288, 256, 0, stream>>>(e1w, we1t, NLAY);
  cvtw_kernel<<<288, 256, 0, stream>>>(e2w, we2t, NLAY);
  cvtw_kernel<<<288, 256, 0, stream>>>(n1w, wn1t, NLAY);
  cvtw_kernel<<<288, 256, 0, stream>>>(n2w, wn2t, NLAY);
  cvt4_kernel<<<2048, 256, 0, stream>>>(x_in, xbA, NNODE * DD / 4);

  const int NB = (NNODE + 255) / 256;  // 391
  hipMemsetAsync(deg, 0, (size_t)NNODE * 4, stream);
  count_kernel<<<(NEDGE + 255) / 256, 256, 0, stream>>>(eidx + NEDGE, deg);
  scan1_kernel<<<NB, 256, 0, stream>>>(deg, locex, bsum);
  scan2_kernel<<<1, 512, 0, stream>>>(bsum, NB);
  scan3_kernel<<<NB, 256, 0, stream>>>(locex, bsum, offs, cur);
  fill_kernel<<<(NEDGE + 255) / 256, 256, 0, stream>>>(eidx, eidx + NEDGE, cur, seid, ssrc);
  if (use_eab)
    gather_cvt_kernel<<<NEDGE / 4, 256, 0, stream>>>(ea_f, seid, eab, NEDGE);

  const int egrid = (NEDGE + 63) / 64;
  const int ngrid = (NNODE + 63) / 64;
  short* xin = xbA;
  short* xout = xbB;
  for (int l = 0; l < NLAY; ++l) {
    if (use_eab) {
      mlp_kernel<true, false><<<egrid, 512, SMEM, stream>>>(
          eab, nullptr, nullptr, nullptr, nullptr,
          we1t + l * 65536, we2t + l * 65536, e1b + l * DD,
          e2b + l * DD, elg + l * DD, elb + l * DD, efeat, nullptr,
          nullptr, NEDGE);
    } else {
      mlp_kernel<false, false><<<egrid, 512, SMEM, stream>>>(
          ea_f, seid, nullptr, nullptr, nullptr,
          we1t + l * 65536, we2t + l * 65536, e1b + l * DD,
          e2b + l * DD, elg + l * DD, elb + l * DD, efeat, nullptr,
          nullptr, NEDGE);
    }
    mlp_kernel<true, true><<<ngrid, 512, SMEM, stream>>>(
        efeat, nullptr, offs, ssrc, xin,
        wn1t + l * 65536, wn2t + l * 65536, n1b + l * DD,
        n2b + l * DD, nlg + l * DD, nlb + l * DD, nullptr,
        (l == NLAY - 1) ? x : nullptr, xout, NNODE);
    short* t = xin; xin = xout; xout = t;
  }
  (void)in_sizes; (void)n_in; (void)out_size; (void)ws_size;
}